// Round 1
// baseline (11030.679 us; speedup 1.0000x reference)
//
#include <hip/hip_runtime.h>
#include <cmath>

// ---------------------------------------------------------------------------
// DeepAR sampling on MI355X. Round 1: correctness-first.
//  - JAX threefry2x32 PRNG reproduced bit-exactly (partitionable mode; flip
//    JAX_PARTITIONABLE to 0 if absmax comes back O(100)).
//  - fp32 everywhere (no MFMA): rejection-sampler accept decisions are
//    knife-edge in d = df/2 - 1/3, so GEMM precision must stay ~1e-6.
// ---------------------------------------------------------------------------

#define JAX_PARTITIONABLE 1

#define HIDDEN 512
#define EMB 40
#define HIST 336
#define PRED 48
#define S_N 8192
#define ENC_BLOCKS 48

// ------------------------------- threefry ----------------------------------
struct KeyPair { unsigned a, b; };

__device__ __forceinline__ unsigned rotl32_(unsigned v, unsigned s) {
  return (v << s) | (v >> (32u - s));
}

__device__ __forceinline__ KeyPair tf2x32(KeyPair k, unsigned x0, unsigned x1) {
  unsigned ks0 = k.a, ks1 = k.b, ks2 = ks0 ^ ks1 ^ 0x1BD11BDAu;
  x0 += ks0; x1 += ks1;
#define TF_R(r) { x0 += x1; x1 = rotl32_(x1, r); x1 ^= x0; }
  TF_R(13u) TF_R(15u) TF_R(26u) TF_R(6u)  x0 += ks1; x1 += ks2 + 1u;
  TF_R(17u) TF_R(29u) TF_R(16u) TF_R(24u) x0 += ks2; x1 += ks0 + 2u;
  TF_R(13u) TF_R(15u) TF_R(26u) TF_R(6u)  x0 += ks0; x1 += ks1 + 3u;
  TF_R(17u) TF_R(29u) TF_R(16u) TF_R(24u) x0 += ks1; x1 += ks2 + 4u;
  TF_R(13u) TF_R(15u) TF_R(26u) TF_R(6u)  x0 += ks2; x1 += ks0 + 5u;
#undef TF_R
  KeyPair r; r.a = x0; r.b = x1; return r;
}

// jax.random.split / random_bits key derivations (mode-dependent).
__device__ __forceinline__ void split2_(KeyPair key, KeyPair& r0, KeyPair& r1) {
#if JAX_PARTITIONABLE
  r0 = tf2x32(key, 0u, 0u);
  r1 = tf2x32(key, 0u, 1u);
#else
  KeyPair p0 = tf2x32(key, 0u, 2u);
  KeyPair p1 = tf2x32(key, 1u, 3u);
  r0.a = p0.a; r0.b = p1.a;
  r1.a = p0.b; r1.b = p1.b;
#endif
}

__device__ __forceinline__ void split3_(KeyPair key, KeyPair& r0, KeyPair& r1, KeyPair& r2) {
#if JAX_PARTITIONABLE
  r0 = tf2x32(key, 0u, 0u);
  r1 = tf2x32(key, 0u, 1u);
  r2 = tf2x32(key, 0u, 2u);
#else
  KeyPair p0 = tf2x32(key, 0u, 3u);
  KeyPair p1 = tf2x32(key, 1u, 4u);
  KeyPair p2 = tf2x32(key, 2u, 5u);
  r0.a = p0.a; r0.b = p1.a;
  r1.a = p2.a; r1.b = p0.b;
  r2.a = p1.b; r2.b = p2.b;
#endif
}

__device__ __forceinline__ unsigned scalar_bits_(KeyPair key) {
#if JAX_PARTITIONABLE
  KeyPair p = tf2x32(key, 0u, 0u);
  return p.a ^ p.b;
#else
  return tf2x32(key, 0u, 0u).a;
#endif
}

__device__ __forceinline__ unsigned batch_bits_8192_(KeyPair key, int s) {
#if JAX_PARTITIONABLE
  KeyPair p = tf2x32(key, 0u, (unsigned)s);
  return p.a ^ p.b;
#else
  if (s < 4096) return tf2x32(key, (unsigned)s, (unsigned)(4096 + s)).a;
  return tf2x32(key, (unsigned)(s - 4096), (unsigned)s).b;
#endif
}

__device__ __forceinline__ KeyPair subkey_of_8192_(KeyPair key, int s) {
#if JAX_PARTITIONABLE
  return tf2x32(key, 0u, (unsigned)s);
#else
  KeyPair r;
  if (s < 4096) {
    r.a = tf2x32(key, (unsigned)(2 * s),     (unsigned)(8192 + 2 * s)).a;
    r.b = tf2x32(key, (unsigned)(2 * s + 1), (unsigned)(8192 + 2 * s + 1)).a;
  } else {
    int m = 2 * s - 8192;
    r.a = tf2x32(key, (unsigned)m,       (unsigned)(m + 8192)).b;
    r.b = tf2x32(key, (unsigned)(m + 1), (unsigned)(m + 1 + 8192)).b;
  }
  return r;
#endif
}

// ------------------------- fp32 numerics (XLA-matched) ---------------------
__device__ __forceinline__ float acc_logf_(float x) {
  return (float)log((double)x);  // correctly-rounded f32 log (matches glibc)
}
__device__ __forceinline__ float acc_expf_(float x) {
  return (float)exp((double)x);
}

__device__ __forceinline__ float bits_to_uniform01_(unsigned bits) {
  return __uint_as_float((bits >> 9) | 0x3F800000u) - 1.0f;
}

// XLA EmitLog1p: |t| < 1e-4 ? (1 + (-0.5)*t)*t : log(t+1)
__device__ __forceinline__ float xla_log1pf_(float t) {
  #pragma clang fp contract(off)
  float small_ = (1.0f + (-0.5f) * t) * t;
  float large_ = acc_logf_(t + 1.0f);
  return (fabsf(t) < 1e-4f) ? small_ : large_;
}

// XLA ErfInv (Giles polynomial), non-FMA evaluation order
__device__ float xla_erfinv_(float x) {
  #pragma clang fp contract(off)
  float w = -xla_log1pf_(-(x * x));
  float p;
  if (w < 5.0f) {
    float ww = w - 2.5f;
    p = 2.81022636e-08f;
    p = 3.43273939e-07f + p * ww;
    p = -3.5233877e-06f + p * ww;
    p = -4.39150654e-06f + p * ww;
    p = 0.00021858087f + p * ww;
    p = -0.00125372503f + p * ww;
    p = -0.00417768164f + p * ww;
    p = 0.246640727f + p * ww;
    p = 1.50140941f + p * ww;
  } else {
    float ww = sqrtf(w) - 3.0f;
    p = -0.000200214257f;
    p = 0.000100950558f + p * ww;
    p = 0.00134934322f + p * ww;
    p = -0.00367342844f + p * ww;
    p = 0.00573950773f + p * ww;
    p = -0.0076224613f + p * ww;
    p = 0.00943887047f + p * ww;
    p = 1.00167406f + p * ww;
    p = 2.83297682f + p * ww;
  }
  return p * x;
}

// jax.random.normal scalar: sqrt(2)*erfinv(uniform(lo=nextafter(-1,0), hi=1))
__device__ float bits_to_normal_(unsigned bits) {
  #pragma clang fp contract(off)
  const float lo = __uint_as_float(0xBF7FFFFFu);
  float f = bits_to_uniform01_(bits);
  float u = f * 2.0f + lo;
  u = fmaxf(lo, u);
  return __uint_as_float(0x3FB504F3u) * xla_erfinv_(u);
}

// jax.nn.softplus = logaddexp(x,0) = max(x,0) + log1p(exp(-|x|))
__device__ __forceinline__ float softplus_(float x) {
  #pragma clang fp contract(off)
  float amax = fmaxf(x, 0.0f);
  float e = acc_expf_(-fabsf(x));
  return amax + xla_log1pf_(e);
}

__device__ __forceinline__ float sigmoid_(float v) { return 1.0f / (1.0f + expf(-v)); }

// ------------------------- gamma / student-t sampler -----------------------
// Marsaglia-Tsang per jax._src.random._gamma_one (alpha >= 1 always here).
__device__ float gamma_sample_(KeyPair gkey, float alpha) {
  #pragma clang fp contract(off)
  const float third = 0.33333334f;
  float d = alpha - third;
  float c = third / sqrtf(d);
  KeyPair key, boost_sub;
  split2_(gkey, key, boost_sub);  // u_boost value unused (alpha>=1)
  (void)boost_sub;
  float X = 0.0f, V = 1.0f, U = 2.0f;
  for (int guard = 0; guard < 1024; guard++) {
    // while-cond: continue if (U >= 1-0.0331 X^4) && (log U >= X/2 + d(1-V+log V))
    float X2 = X * X;
    float sq = 1.0f - 0.0331f * (X2 * X2);
    bool cont = false;
    if (U >= sq) {
      float lhs = acc_logf_(U);
      float rhs = (X * 0.5f) + (d * ((1.0f - V) + acc_logf_(V)));
      cont = (lhs >= rhs);
    }
    if (!cont) break;
    KeyPair nkey, xkey, Ukey;
    split3_(key, nkey, xkey, Ukey);
    key = nkey;
    float x, v;
    KeyPair kk = xkey;
    do {
      KeyPair knew, sub;
      split2_(kk, knew, sub);
      kk = knew;
      x = bits_to_normal_(scalar_bits_(sub));
      v = 1.0f + x * c;
    } while (v <= 0.0f);
    X = x * x;
    V = (v * v) * v;
    U = bits_to_uniform01_(scalar_bits_(Ukey));
  }
  return d * V;
}

// jax.random.t(fold_in(key(42), k), df, (8192,1)) for element s
__device__ float sample_t_eps_(int k, int s, float df) {
  #pragma clang fp contract(off)
  KeyPair base; base.a = 0u; base.b = 42u;
  KeyPair tkey = tf2x32(base, 0u, (unsigned)k);  // fold_in (mode-independent)
  KeyPair key_n, key_g;
  split2_(tkey, key_n, key_g);
  float n = bits_to_normal_(batch_bits_8192_(key_n, s));
  KeyPair gkey = subkey_of_8192_(key_g, s);
  float half_df = df * 0.5f;
  float g = gamma_sample_(gkey, half_df);
  return n * sqrtf(half_df / g);
}

// ------------------------------- kernels -----------------------------------

// K0: scale, tfe (enc time-feature emb), emb_y (dec time-feature emb), sync=0
__global__ __launch_bounds__(256) void prep_kernel(
    const float* __restrict__ x, const float* __restrict__ x_mark,
    const float* __restrict__ y_mark, const float* __restrict__ W_emb,
    const float* __restrict__ b_emb, float* __restrict__ scale_p,
    float* __restrict__ tfe, float* __restrict__ emb_y,
    unsigned* __restrict__ syncc) {
  int tid = threadIdx.x;
  if (tid == 0) {
    float s = 0.0f;
    for (int t = 0; t < HIST; t++) s += fabsf(x[t]);
    float m = s / 336.0f;
    scale_p[0] = fmaxf(m, 1e-5f);
    *syncc = 0u;
  }
  for (int idx = tid; idx < HIST * EMB; idx += 256) {
    int t = idx / EMB, e = idx % EMB;
    float a = b_emb[e];
    for (int f = 0; f < 4; f++) a += x_mark[t * 4 + f] * W_emb[e * 4 + f];
    tfe[idx] = a;
  }
  for (int idx = tid; idx < PRED * EMB; idx += 256) {
    int kk = idx / EMB, e = idx % EMB;
    float a = b_emb[e];
    for (int f = 0; f < 4; f++) a += y_mark[kk * 4 + f] * W_emb[e * 4 + f];
    emb_y[idx] = a;
  }
}

// K1: encoder input-side gates gi[t][1536] = W_ih @ [x_t/scale, tfe_t] + b_ih
__global__ __launch_bounds__(256) void enc_gi_kernel(
    const float* __restrict__ x, const float* __restrict__ tfe,
    const float* __restrict__ W_ih, const float* __restrict__ b_ih,
    const float* __restrict__ scale_p, float* __restrict__ enc_gi) {
  __shared__ float fe[EMB];
  __shared__ float xs_s;
  int t = blockIdx.x;
  int tid = threadIdx.x;
  if (tid < EMB) fe[tid] = tfe[t * EMB + tid];
  if (tid == 0) xs_s = x[t] / scale_p[0];
  __syncthreads();
  float xs = xs_s;
  for (int r = tid; r < 3 * HIDDEN; r += 256) {
    const float* wr = W_ih + (size_t)r * 41;
    float a = b_ih[r] + wr[0] * xs;
    #pragma unroll
    for (int e = 0; e < EMB; e++) a += wr[1 + e] * fe[e];
    enc_gi[(size_t)t * 1536 + r] = a;
  }
}

// K1b: decoder per-step constant input gates giy[k][1536]
__global__ __launch_bounds__(256) void giy_kernel(
    const float* __restrict__ emb_y, const float* __restrict__ W_ih,
    const float* __restrict__ b_ih, float* __restrict__ giy) {
  __shared__ float fe[EMB];
  int k = blockIdx.x;
  int tid = threadIdx.x;
  if (tid < EMB) fe[tid] = emb_y[k * EMB + tid];
  __syncthreads();
  for (int r = tid; r < 3 * HIDDEN; r += 256) {
    const float* wr = W_ih + (size_t)r * 41;
    float a = b_ih[r];
    #pragma unroll
    for (int e = 0; e < EMB; e++) a += wr[1 + e] * fe[e];
    giy[(size_t)k * 1536 + r] = a;
  }
}

// K2: persistent encoder GRU. 48 blocks x 256 threads; W_hh register-resident
// (row = gtid/8, 64 cols per thread). One manual grid-sync per step.
__global__ __launch_bounds__(256) void enc_gru_kernel(
    const float* __restrict__ enc_gi, const float* __restrict__ W_hh,
    const float* __restrict__ b_hh, float* __restrict__ ghbuf,
    unsigned* __restrict__ syncc, float* __restrict__ h_T) {
  __shared__ __align__(16) float hs[HIDDEN];
  int tid = threadIdx.x;
  int gtid = blockIdx.x * 256 + tid;
  int row = gtid >> 3;
  int sub = gtid & 7;

  float w[64];
  const float* wp = W_hh + (size_t)row * HIDDEN + sub * 64;
  #pragma unroll
  for (int i = 0; i < 16; i++) {
    float4 v = *(const float4*)(wp + 4 * i);
    w[4 * i + 0] = v.x; w[4 * i + 1] = v.y; w[4 * i + 2] = v.z; w[4 * i + 3] = v.w;
  }
  if (tid < 128) *(float4*)&hs[tid * 4] = make_float4(0.f, 0.f, 0.f, 0.f);
  float bhr0 = b_hh[tid],       bhz0 = b_hh[512 + tid],  bhn0 = b_hh[1024 + tid];
  float bhr1 = b_hh[256 + tid], bhz1 = b_hh[768 + tid],  bhn1 = b_hh[1280 + tid];
  __syncthreads();

  for (int t = 0; t < HIST; t++) {
    // gh partial: 64-wide chunk of row dot h
    float p = 0.0f;
    const float4* hv = (const float4*)&hs[sub * 64];
    #pragma unroll
    for (int i = 0; i < 16; i++) {
      float4 v = hv[i];
      p += w[4 * i + 0] * v.x + w[4 * i + 1] * v.y +
           w[4 * i + 2] * v.z + w[4 * i + 3] * v.w;
    }
    p += __shfl_xor(p, 1, 64);
    p += __shfl_xor(p, 2, 64);
    p += __shfl_xor(p, 4, 64);
    int par = t & 1;
    if (sub == 0)
      __hip_atomic_store(&ghbuf[par * 1536 + row], p, __ATOMIC_RELAXED,
                         __HIP_MEMORY_SCOPE_AGENT);
    // grid sync (phase t+1)
    __syncthreads();
    if (tid == 0) {
      __hip_atomic_fetch_add(syncc, 1u, __ATOMIC_RELEASE, __HIP_MEMORY_SCOPE_AGENT);
      unsigned tgtv = (unsigned)ENC_BLOCKS * (unsigned)(t + 1);
      while (__hip_atomic_load(syncc, __ATOMIC_ACQUIRE, __HIP_MEMORY_SCOPE_AGENT) < tgtv)
        __builtin_amdgcn_s_sleep(2);
    }
    __syncthreads();
    // redundant (deterministic) h update per block
    float hn0, hn1;
    {
      int j = tid;
      float ghr = __hip_atomic_load(&ghbuf[par * 1536 + j], __ATOMIC_RELAXED, __HIP_MEMORY_SCOPE_AGENT);
      float ghz = __hip_atomic_load(&ghbuf[par * 1536 + 512 + j], __ATOMIC_RELAXED, __HIP_MEMORY_SCOPE_AGENT);
      float ghn = __hip_atomic_load(&ghbuf[par * 1536 + 1024 + j], __ATOMIC_RELAXED, __HIP_MEMORY_SCOPE_AGENT);
      float gir = enc_gi[(size_t)t * 1536 + j];
      float giz = enc_gi[(size_t)t * 1536 + 512 + j];
      float gin = enc_gi[(size_t)t * 1536 + 1024 + j];
      float r = sigmoid_(gir + (ghr + bhr0));
      float z = sigmoid_(giz + (ghz + bhz0));
      float n = tanhf(gin + r * (ghn + bhn0));
      hn0 = (1.0f - z) * n + z * hs[j];
    }
    {
      int j = tid + 256;
      float ghr = __hip_atomic_load(&ghbuf[par * 1536 + j], __ATOMIC_RELAXED, __HIP_MEMORY_SCOPE_AGENT);
      float ghz = __hip_atomic_load(&ghbuf[par * 1536 + 512 + j], __ATOMIC_RELAXED, __HIP_MEMORY_SCOPE_AGENT);
      float ghn = __hip_atomic_load(&ghbuf[par * 1536 + 1024 + j], __ATOMIC_RELAXED, __HIP_MEMORY_SCOPE_AGENT);
      float gir = enc_gi[(size_t)t * 1536 + j];
      float giz = enc_gi[(size_t)t * 1536 + 512 + j];
      float gin = enc_gi[(size_t)t * 1536 + 1024 + j];
      float r = sigmoid_(gir + (ghr + bhr1));
      float z = sigmoid_(giz + (ghz + bhz1));
      float n = tanhf(gin + r * (ghn + bhn1));
      hn1 = (1.0f - z) * n + z * hs[j];
    }
    hs[tid] = hn0;
    hs[tid + 256] = hn1;
    __syncthreads();
  }
  if (blockIdx.x == 0 && tid < 128)
    *(float4*)&h_T[tid * 4] = *(float4*)&hs[tid * 4];
}

// K3: decoder GRU cell, one step. C = h(8192x512) @ W_hh^T fused with gates.
// Block tile: 128 samples x 32 hidden (x3 gate slices). 256 threads, 48 acc.
#define BM 128
#define BN 32
#define BK 32
__global__ __launch_bounds__(256) void dec_gru_kernel(
    const float* __restrict__ h_prev, int bcast,
    const float* __restrict__ tgt, int tgt_is_x,
    const float* __restrict__ giy_k, const float* __restrict__ W_hh,
    const float* __restrict__ b_hh, const float* __restrict__ W_ih,
    float* __restrict__ h_out) {
  __shared__ __align__(16) float As[BK][BM + 4];
  __shared__ __align__(16) float Bs[3][BK][BN + 2];
  int bs = blockIdx.x;
  int bj = blockIdx.y;
  int tid = threadIdx.x;
  int s0 = bs * BM;
  int j0 = bj * BN;
  int tx = tid & 15;   // 16 j-groups x 2 j
  int ty = tid >> 4;   // 16 s-groups x 8 s

  float acc[3][8][2];
  #pragma unroll
  for (int t = 0; t < 3; t++)
    #pragma unroll
    for (int i = 0; i < 8; i++) { acc[t][i][0] = 0.f; acc[t][i][1] = 0.f; }

  for (int kb = 0; kb < HIDDEN; kb += BK) {
    #pragma unroll
    for (int i = 0; i < 4; i++) {
      int slot = tid + 256 * i;           // 1024 float4 slots: 128 rows x 8
      int rrow = slot >> 3;
      int c4 = slot & 7;
      const float* src = bcast ? (h_prev + kb + c4 * 4)
                               : (h_prev + (size_t)(s0 + rrow) * HIDDEN + kb + c4 * 4);
      float4 v = *(const float4*)src;
      As[c4 * 4 + 0][rrow] = v.x;
      As[c4 * 4 + 1][rrow] = v.y;
      As[c4 * 4 + 2][rrow] = v.z;
      As[c4 * 4 + 3][rrow] = v.w;
    }
    {
      int rrow = tid >> 3;                // 32 rows x 8 float4 per slice
      int c4 = tid & 7;
      #pragma unroll
      for (int t = 0; t < 3; t++) {
        const float* src = W_hh + (size_t)(j0 + t * 512 + rrow) * HIDDEN + kb + c4 * 4;
        float4 v = *(const float4*)src;
        Bs[t][c4 * 4 + 0][rrow] = v.x;
        Bs[t][c4 * 4 + 1][rrow] = v.y;
        Bs[t][c4 * 4 + 2][rrow] = v.z;
        Bs[t][c4 * 4 + 3][rrow] = v.w;
      }
    }
    __syncthreads();
    #pragma unroll 8
    for (int kk = 0; kk < BK; kk++) {
      float a[8];
      *(float4*)&a[0] = *(float4*)&As[kk][ty * 8];
      *(float4*)&a[4] = *(float4*)&As[kk][ty * 8 + 4];
      float b0[3][2];
      #pragma unroll
      for (int t = 0; t < 3; t++) {
        b0[t][0] = Bs[t][kk][tx * 2];
        b0[t][1] = Bs[t][kk][tx * 2 + 1];
      }
      #pragma unroll
      for (int t = 0; t < 3; t++)
        #pragma unroll
        for (int si = 0; si < 8; si++) {
          acc[t][si][0] += a[si] * b0[t][0];
          acc[t][si][1] += a[si] * b0[t][1];
        }
    }
    __syncthreads();
  }

  // epilogue: gates + h update
  int s_base = s0 + ty * 8;
  #pragma unroll
  for (int jj = 0; jj < 2; jj++) {
    int j = j0 + tx * 2 + jj;
    float giy_r = giy_k[j];
    float giy_z = giy_k[512 + j];
    float giy_n = giy_k[1024 + j];
    float w0r = W_ih[(size_t)j * 41];
    float w0z = W_ih[(size_t)(512 + j) * 41];
    float w0n = W_ih[(size_t)(1024 + j) * 41];
    float bhr = b_hh[j], bhz = b_hh[512 + j], bhn = b_hh[1024 + j];
    #pragma unroll
    for (int si = 0; si < 8; si++) {
      int s = s_base + si;
      float tg = tgt_is_x ? tgt[HIST - 1] : tgt[s];
      float h_old = bcast ? h_prev[j] : h_prev[(size_t)s * HIDDEN + j];
      float gr = (giy_r + w0r * tg) + (acc[0][si][jj] + bhr);
      float gz = (giy_z + w0z * tg) + (acc[1][si][jj] + bhz);
      float gn_i = giy_n + w0n * tg;
      float gn_h = acc[2][si][jj] + bhn;
      float r = sigmoid_(gr);
      float z = sigmoid_(gz);
      float n = tanhf(gn_i + r * gn_h);
      h_out[(size_t)s * HIDDEN + j] = (1.0f - z) * n + z * h_old;
    }
  }
}

// K4: heads (df/loc/sc) + student-t sampling + output/tgt write
__global__ __launch_bounds__(256) void dec_head_kernel(
    const float* __restrict__ h, const float* __restrict__ W_df,
    const float* __restrict__ b_df, const float* __restrict__ W_loc,
    const float* __restrict__ b_loc, const float* __restrict__ W_sc,
    const float* __restrict__ b_sc, const float* __restrict__ scale_p,
    float* __restrict__ tgt, float* __restrict__ out, int k) {
  #pragma clang fp contract(off)
  int s = blockIdx.x * 256 + threadIdx.x;
  if (s >= S_N) return;
  const float4* hv = (const float4*)(h + (size_t)s * HIDDEN);
  float adf = 0.f, alo = 0.f, asc = 0.f;
  for (int i = 0; i < HIDDEN / 4; i++) {
    float4 xv = hv[i];
    float4 wd = ((const float4*)W_df)[i];
    float4 wl = ((const float4*)W_loc)[i];
    float4 wsv = ((const float4*)W_sc)[i];
    adf += xv.x * wd.x;  adf += xv.y * wd.y;  adf += xv.z * wd.z;  adf += xv.w * wd.w;
    alo += xv.x * wl.x;  alo += xv.y * wl.y;  alo += xv.z * wl.z;  alo += xv.w * wl.w;
    asc += xv.x * wsv.x; asc += xv.y * wsv.y; asc += xv.z * wsv.z; asc += xv.w * wsv.w;
  }
  float df = 2.0f + softplus_(adf + b_df[0]);
  float loc = alo + b_loc[0];
  float sc = softplus_(asc + b_sc[0]);
  float eps = sample_t_eps_(k, s, df);
  float smp = (loc + sc * eps) * scale_p[0];
  out[(size_t)s * PRED + k] = smp;
  tgt[s] = smp;
}

// ------------------------------- launcher ----------------------------------
extern "C" void kernel_launch(void* const* d_in, const int* in_sizes, int n_in,
                              void* d_out, int out_size, void* d_ws, size_t ws_size,
                              hipStream_t stream) {
  const float* x      = (const float*)d_in[0];
  const float* x_mark = (const float*)d_in[1];
  const float* y_mark = (const float*)d_in[2];
  const float* W_emb  = (const float*)d_in[4];
  const float* b_emb  = (const float*)d_in[5];
  const float* W_ih   = (const float*)d_in[6];
  const float* W_hh   = (const float*)d_in[7];
  const float* b_ih   = (const float*)d_in[8];
  const float* b_hh   = (const float*)d_in[9];
  const float* W_df   = (const float*)d_in[10];
  const float* b_df   = (const float*)d_in[11];
  const float* W_loc  = (const float*)d_in[12];
  const float* b_loc  = (const float*)d_in[13];
  const float* W_sc   = (const float*)d_in[14];
  const float* b_sc   = (const float*)d_in[15];
  float* out = (float*)d_out;

  float* w = (float*)d_ws;
  float* h_a    = w + 0;                    // 8192*512
  float* h_b    = w + 4194304;              // 8192*512
  float* enc_gi = w + 8388608;              // 336*1536
  float* giy    = w + 8904704;              // 48*1536
  float* tfe    = w + 8978432;              // 336*40
  float* emb_y  = w + 8991872;              // 48*40
  float* ghbuf  = w + 8993792;              // 2*1536
  float* h_T    = w + 8996864;              // 512
  float* tgt    = w + 8997376;              // 8192
  float* scale_p = w + 9005568;             // 1
  unsigned* syncc = (unsigned*)(w + 9005569);

  prep_kernel<<<1, 256, 0, stream>>>(x, x_mark, y_mark, W_emb, b_emb,
                                     scale_p, tfe, emb_y, syncc);
  enc_gi_kernel<<<HIST, 256, 0, stream>>>(x, tfe, W_ih, b_ih, scale_p, enc_gi);
  giy_kernel<<<PRED, 256, 0, stream>>>(emb_y, W_ih, b_ih, giy);
  enc_gru_kernel<<<ENC_BLOCKS, 256, 0, stream>>>(enc_gi, W_hh, b_hh, ghbuf,
                                                 syncc, h_T);
  for (int k = 0; k < PRED; k++) {
    const float* h_in = (k == 0) ? h_T : ((k & 1) ? h_a : h_b);
    float* h_o = (k & 1) ? h_b : h_a;
    dec_gru_kernel<<<dim3(S_N / BM, HIDDEN / BN), 256, 0, stream>>>(
        h_in, (k == 0) ? 1 : 0, (k == 0) ? x : tgt, (k == 0) ? 1 : 0,
        giy + (size_t)k * 1536, W_hh, b_hh, W_ih, h_o);
    dec_head_kernel<<<S_N / 256, 256, 0, stream>>>(
        h_o, W_df, b_df, W_loc, b_loc, W_sc, b_sc, scale_p, tgt, out, k);
  }
}

// Round 2
// 7548.982 us; speedup vs baseline: 1.4612x; 1.4612x over previous
//
#include <hip/hip_runtime.h>
#include <cmath>

// ---------------------------------------------------------------------------
// DeepAR sampling on MI355X. Round 2: decoder GEMM -> bf16 MFMA, 3-way split
// (hi/mid/lo, 6 products, fp32 accumulate). Split error ~2^-25 < fp32
// dot-ordering noise, so gamma-rejection flip statistics match round 1.
// Encoder unchanged (grid-sync GRU). ws usage ~57.5 MB.
// ---------------------------------------------------------------------------

#define JAX_PARTITIONABLE 1

#define HIDDEN 512
#define EMB 40
#define HIST 336
#define PRED 48
#define S_N 8192
#define ENC_BLOCKS 48

#define HPLANE (8192 * 512)     // shorts per h split plane
#define WPLANE (1536 * 512)     // shorts per W split plane

typedef __attribute__((ext_vector_type(8))) short short8;
typedef __attribute__((ext_vector_type(4))) float f32x4;

// ------------------------------- threefry ----------------------------------
struct KeyPair { unsigned a, b; };

__device__ __forceinline__ unsigned rotl32_(unsigned v, unsigned s) {
  return (v << s) | (v >> (32u - s));
}

__device__ __forceinline__ KeyPair tf2x32(KeyPair k, unsigned x0, unsigned x1) {
  unsigned ks0 = k.a, ks1 = k.b, ks2 = ks0 ^ ks1 ^ 0x1BD11BDAu;
  x0 += ks0; x1 += ks1;
#define TF_R(r) { x0 += x1; x1 = rotl32_(x1, r); x1 ^= x0; }
  TF_R(13u) TF_R(15u) TF_R(26u) TF_R(6u)  x0 += ks1; x1 += ks2 + 1u;
  TF_R(17u) TF_R(29u) TF_R(16u) TF_R(24u) x0 += ks2; x1 += ks0 + 2u;
  TF_R(13u) TF_R(15u) TF_R(26u) TF_R(6u)  x0 += ks0; x1 += ks1 + 3u;
  TF_R(17u) TF_R(29u) TF_R(16u) TF_R(24u) x0 += ks1; x1 += ks2 + 4u;
  TF_R(13u) TF_R(15u) TF_R(26u) TF_R(6u)  x0 += ks2; x1 += ks0 + 5u;
#undef TF_R
  KeyPair r; r.a = x0; r.b = x1; return r;
}

__device__ __forceinline__ void split2_(KeyPair key, KeyPair& r0, KeyPair& r1) {
#if JAX_PARTITIONABLE
  r0 = tf2x32(key, 0u, 0u);
  r1 = tf2x32(key, 0u, 1u);
#else
  KeyPair p0 = tf2x32(key, 0u, 2u);
  KeyPair p1 = tf2x32(key, 1u, 3u);
  r0.a = p0.a; r0.b = p1.a;
  r1.a = p0.b; r1.b = p1.b;
#endif
}

__device__ __forceinline__ void split3_(KeyPair key, KeyPair& r0, KeyPair& r1, KeyPair& r2) {
#if JAX_PARTITIONABLE
  r0 = tf2x32(key, 0u, 0u);
  r1 = tf2x32(key, 0u, 1u);
  r2 = tf2x32(key, 0u, 2u);
#else
  KeyPair p0 = tf2x32(key, 0u, 3u);
  KeyPair p1 = tf2x32(key, 1u, 4u);
  KeyPair p2 = tf2x32(key, 2u, 5u);
  r0.a = p0.a; r0.b = p1.a;
  r1.a = p2.a; r1.b = p0.b;
  r2.a = p1.b; r2.b = p2.b;
#endif
}

__device__ __forceinline__ unsigned scalar_bits_(KeyPair key) {
#if JAX_PARTITIONABLE
  KeyPair p = tf2x32(key, 0u, 0u);
  return p.a ^ p.b;
#else
  return tf2x32(key, 0u, 0u).a;
#endif
}

__device__ __forceinline__ unsigned batch_bits_8192_(KeyPair key, int s) {
#if JAX_PARTITIONABLE
  KeyPair p = tf2x32(key, 0u, (unsigned)s);
  return p.a ^ p.b;
#else
  if (s < 4096) return tf2x32(key, (unsigned)s, (unsigned)(4096 + s)).a;
  return tf2x32(key, (unsigned)(s - 4096), (unsigned)s).b;
#endif
}

__device__ __forceinline__ KeyPair subkey_of_8192_(KeyPair key, int s) {
#if JAX_PARTITIONABLE
  return tf2x32(key, 0u, (unsigned)s);
#else
  KeyPair r;
  if (s < 4096) {
    r.a = tf2x32(key, (unsigned)(2 * s),     (unsigned)(8192 + 2 * s)).a;
    r.b = tf2x32(key, (unsigned)(2 * s + 1), (unsigned)(8192 + 2 * s + 1)).a;
  } else {
    int m = 2 * s - 8192;
    r.a = tf2x32(key, (unsigned)m,       (unsigned)(m + 8192)).b;
    r.b = tf2x32(key, (unsigned)(m + 1), (unsigned)(m + 1 + 8192)).b;
  }
  return r;
#endif
}

// ------------------------- fp32 numerics (XLA-matched) ---------------------
__device__ __forceinline__ float acc_logf_(float x) {
  return (float)log((double)x);
}
__device__ __forceinline__ float acc_expf_(float x) {
  return (float)exp((double)x);
}

__device__ __forceinline__ float bits_to_uniform01_(unsigned bits) {
  return __uint_as_float((bits >> 9) | 0x3F800000u) - 1.0f;
}

__device__ __forceinline__ float xla_log1pf_(float t) {
  #pragma clang fp contract(off)
  float small_ = (1.0f + (-0.5f) * t) * t;
  float large_ = acc_logf_(t + 1.0f);
  return (fabsf(t) < 1e-4f) ? small_ : large_;
}

__device__ float xla_erfinv_(float x) {
  #pragma clang fp contract(off)
  float w = -xla_log1pf_(-(x * x));
  float p;
  if (w < 5.0f) {
    float ww = w - 2.5f;
    p = 2.81022636e-08f;
    p = 3.43273939e-07f + p * ww;
    p = -3.5233877e-06f + p * ww;
    p = -4.39150654e-06f + p * ww;
    p = 0.00021858087f + p * ww;
    p = -0.00125372503f + p * ww;
    p = -0.00417768164f + p * ww;
    p = 0.246640727f + p * ww;
    p = 1.50140941f + p * ww;
  } else {
    float ww = sqrtf(w) - 3.0f;
    p = -0.000200214257f;
    p = 0.000100950558f + p * ww;
    p = 0.00134934322f + p * ww;
    p = -0.00367342844f + p * ww;
    p = 0.00573950773f + p * ww;
    p = -0.0076224613f + p * ww;
    p = 0.00943887047f + p * ww;
    p = 1.00167406f + p * ww;
    p = 2.83297682f + p * ww;
  }
  return p * x;
}

__device__ float bits_to_normal_(unsigned bits) {
  #pragma clang fp contract(off)
  const float lo = __uint_as_float(0xBF7FFFFFu);
  float f = bits_to_uniform01_(bits);
  float u = f * 2.0f + lo;
  u = fmaxf(lo, u);
  return __uint_as_float(0x3FB504F3u) * xla_erfinv_(u);
}

__device__ __forceinline__ float softplus_(float x) {
  #pragma clang fp contract(off)
  float amax = fmaxf(x, 0.0f);
  float e = acc_expf_(-fabsf(x));
  return amax + xla_log1pf_(e);
}

__device__ __forceinline__ float sigmoid_(float v) { return 1.0f / (1.0f + expf(-v)); }

// bf16 round-to-nearest-even split helpers
__device__ __forceinline__ unsigned short f2bf_(float f) {
  unsigned u = __float_as_uint(f);
  unsigned r = (u + 0x7FFFu + ((u >> 16) & 1u)) >> 16;
  return (unsigned short)r;
}
__device__ __forceinline__ float bf2f_(unsigned short b) {
  return __uint_as_float(((unsigned)b) << 16);
}

// ------------------------- gamma / student-t sampler -----------------------
__device__ float gamma_sample_(KeyPair gkey, float alpha) {
  #pragma clang fp contract(off)
  const float third = 0.33333334f;
  float d = alpha - third;
  float c = third / sqrtf(d);
  KeyPair key, boost_sub;
  split2_(gkey, key, boost_sub);
  (void)boost_sub;
  float X = 0.0f, V = 1.0f, U = 2.0f;
  for (int guard = 0; guard < 1024; guard++) {
    float X2 = X * X;
    float sq = 1.0f - 0.0331f * (X2 * X2);
    bool cont = false;
    if (U >= sq) {
      float lhs = acc_logf_(U);
      float rhs = (X * 0.5f) + (d * ((1.0f - V) + acc_logf_(V)));
      cont = (lhs >= rhs);
    }
    if (!cont) break;
    KeyPair nkey, xkey, Ukey;
    split3_(key, nkey, xkey, Ukey);
    key = nkey;
    float x, v;
    KeyPair kk = xkey;
    do {
      KeyPair knew, sub;
      split2_(kk, knew, sub);
      kk = knew;
      x = bits_to_normal_(scalar_bits_(sub));
      v = 1.0f + x * c;
    } while (v <= 0.0f);
    X = x * x;
    V = (v * v) * v;
    U = bits_to_uniform01_(scalar_bits_(Ukey));
  }
  return d * V;
}

__device__ float sample_t_eps_(int k, int s, float df) {
  #pragma clang fp contract(off)
  KeyPair base; base.a = 0u; base.b = 42u;
  KeyPair tkey = tf2x32(base, 0u, (unsigned)k);
  KeyPair key_n, key_g;
  split2_(tkey, key_n, key_g);
  float n = bits_to_normal_(batch_bits_8192_(key_n, s));
  KeyPair gkey = subkey_of_8192_(key_g, s);
  float half_df = df * 0.5f;
  float g = gamma_sample_(gkey, half_df);
  return n * sqrtf(half_df / g);
}

// ------------------------------- kernels -----------------------------------

__global__ __launch_bounds__(256) void prep_kernel(
    const float* __restrict__ x, const float* __restrict__ x_mark,
    const float* __restrict__ y_mark, const float* __restrict__ W_emb,
    const float* __restrict__ b_emb, float* __restrict__ scale_p,
    float* __restrict__ tfe, float* __restrict__ emb_y,
    unsigned* __restrict__ syncc) {
  int tid = threadIdx.x;
  if (tid == 0) {
    float s = 0.0f;
    for (int t = 0; t < HIST; t++) s += fabsf(x[t]);
    float m = s / 336.0f;
    scale_p[0] = fmaxf(m, 1e-5f);
    *syncc = 0u;
  }
  for (int idx = tid; idx < HIST * EMB; idx += 256) {
    int t = idx / EMB, e = idx % EMB;
    float a = b_emb[e];
    for (int f = 0; f < 4; f++) a += x_mark[t * 4 + f] * W_emb[e * 4 + f];
    tfe[idx] = a;
  }
  for (int idx = tid; idx < PRED * EMB; idx += 256) {
    int kk = idx / EMB, e = idx % EMB;
    float a = b_emb[e];
    for (int f = 0; f < 4; f++) a += y_mark[kk * 4 + f] * W_emb[e * 4 + f];
    emb_y[idx] = a;
  }
}

__global__ __launch_bounds__(256) void enc_gi_kernel(
    const float* __restrict__ x, const float* __restrict__ tfe,
    const float* __restrict__ W_ih, const float* __restrict__ b_ih,
    const float* __restrict__ scale_p, float* __restrict__ enc_gi) {
  __shared__ float fe[EMB];
  __shared__ float xs_s;
  int t = blockIdx.x;
  int tid = threadIdx.x;
  if (tid < EMB) fe[tid] = tfe[t * EMB + tid];
  if (tid == 0) xs_s = x[t] / scale_p[0];
  __syncthreads();
  float xs = xs_s;
  for (int r = tid; r < 3 * HIDDEN; r += 256) {
    const float* wr = W_ih + (size_t)r * 41;
    float a = b_ih[r] + wr[0] * xs;
    #pragma unroll
    for (int e = 0; e < EMB; e++) a += wr[1 + e] * fe[e];
    enc_gi[(size_t)t * 1536 + r] = a;
  }
}

__global__ __launch_bounds__(256) void giy_kernel(
    const float* __restrict__ emb_y, const float* __restrict__ W_ih,
    const float* __restrict__ b_ih, float* __restrict__ giy) {
  __shared__ float fe[EMB];
  int k = blockIdx.x;
  int tid = threadIdx.x;
  if (tid < EMB) fe[tid] = emb_y[k * EMB + tid];
  __syncthreads();
  for (int r = tid; r < 3 * HIDDEN; r += 256) {
    const float* wr = W_ih + (size_t)r * 41;
    float a = b_ih[r];
    #pragma unroll
    for (int e = 0; e < EMB; e++) a += wr[1 + e] * fe[e];
    giy[(size_t)k * 1536 + r] = a;
  }
}

// W_hh -> 3 bf16 split planes, rearranged per jb-slab: Wr[sp][jb][g*64+jl][k]
__global__ __launch_bounds__(256) void wsplit_kernel(
    const float* __restrict__ W_hh, unsigned short* __restrict__ Wr) {
  int row = blockIdx.x;                 // 0..1535
  int g = row >> 9;
  int jg = row & 511;
  int jb = jg >> 6, jl = jg & 63;
  size_t dst = ((size_t)jb * 192 + g * 64 + jl) * 512;
  for (int k = threadIdx.x; k < 512; k += 256) {
    float w = W_hh[(size_t)row * 512 + k];
    unsigned short b0 = f2bf_(w);  float r1 = w - bf2f_(b0);
    unsigned short b1 = f2bf_(r1); float r2 = r1 - bf2f_(b1);
    unsigned short b2 = f2bf_(r2);
    Wr[dst + k] = b0;
    Wr[WPLANE + dst + k] = b1;
    Wr[2 * WPLANE + dst + k] = b2;
  }
}

// split h_T (512) into sT[3][512]
__global__ __launch_bounds__(256) void hsplit_kernel(
    const float* __restrict__ h_T, unsigned short* __restrict__ sT) {
  int i = threadIdx.x;
  for (int j = i; j < 512; j += 256) {
    float v = h_T[j];
    unsigned short b0 = f2bf_(v);  float r1 = v - bf2f_(b0);
    unsigned short b1 = f2bf_(r1); float r2 = r1 - bf2f_(b1);
    unsigned short b2 = f2bf_(r2);
    sT[j] = b0; sT[512 + j] = b1; sT[1024 + j] = b2;
  }
}

// broadcast sT rows into h3[3][8192][512]
__global__ __launch_bounds__(256) void h3bcast_kernel(
    const unsigned short* __restrict__ sT, unsigned short* __restrict__ h3) {
  int row = blockIdx.x;
  int tid = threadIdx.x;
  if (tid < 192) {
    int sp = tid >> 6, c = tid & 63;
    ((uint4*)(h3 + (size_t)sp * HPLANE + (size_t)row * 512))[c] =
        ((const uint4*)(sT + sp * 512))[c];
  }
}

// persistent encoder GRU (unchanged from round 1)
__global__ __launch_bounds__(256) void enc_gru_kernel(
    const float* __restrict__ enc_gi, const float* __restrict__ W_hh,
    const float* __restrict__ b_hh, float* __restrict__ ghbuf,
    unsigned* __restrict__ syncc, float* __restrict__ h_T) {
  __shared__ __align__(16) float hs[HIDDEN];
  int tid = threadIdx.x;
  int gtid = blockIdx.x * 256 + tid;
  int row = gtid >> 3;
  int sub = gtid & 7;

  float w[64];
  const float* wp = W_hh + (size_t)row * HIDDEN + sub * 64;
  #pragma unroll
  for (int i = 0; i < 16; i++) {
    float4 v = *(const float4*)(wp + 4 * i);
    w[4 * i + 0] = v.x; w[4 * i + 1] = v.y; w[4 * i + 2] = v.z; w[4 * i + 3] = v.w;
  }
  if (tid < 128) *(float4*)&hs[tid * 4] = make_float4(0.f, 0.f, 0.f, 0.f);
  float bhr0 = b_hh[tid],       bhz0 = b_hh[512 + tid],  bhn0 = b_hh[1024 + tid];
  float bhr1 = b_hh[256 + tid], bhz1 = b_hh[768 + tid],  bhn1 = b_hh[1280 + tid];
  __syncthreads();

  for (int t = 0; t < HIST; t++) {
    float p = 0.0f;
    const float4* hv = (const float4*)&hs[sub * 64];
    #pragma unroll
    for (int i = 0; i < 16; i++) {
      float4 v = hv[i];
      p += w[4 * i + 0] * v.x + w[4 * i + 1] * v.y +
           w[4 * i + 2] * v.z + w[4 * i + 3] * v.w;
    }
    p += __shfl_xor(p, 1, 64);
    p += __shfl_xor(p, 2, 64);
    p += __shfl_xor(p, 4, 64);
    int par = t & 1;
    if (sub == 0)
      __hip_atomic_store(&ghbuf[par * 1536 + row], p, __ATOMIC_RELAXED,
                         __HIP_MEMORY_SCOPE_AGENT);
    __syncthreads();
    if (tid == 0) {
      __hip_atomic_fetch_add(syncc, 1u, __ATOMIC_RELEASE, __HIP_MEMORY_SCOPE_AGENT);
      unsigned tgtv = (unsigned)ENC_BLOCKS * (unsigned)(t + 1);
      while (__hip_atomic_load(syncc, __ATOMIC_ACQUIRE, __HIP_MEMORY_SCOPE_AGENT) < tgtv)
        __builtin_amdgcn_s_sleep(2);
    }
    __syncthreads();
    float hn0, hn1;
    {
      int j = tid;
      float ghr = __hip_atomic_load(&ghbuf[par * 1536 + j], __ATOMIC_RELAXED, __HIP_MEMORY_SCOPE_AGENT);
      float ghz = __hip_atomic_load(&ghbuf[par * 1536 + 512 + j], __ATOMIC_RELAXED, __HIP_MEMORY_SCOPE_AGENT);
      float ghn = __hip_atomic_load(&ghbuf[par * 1536 + 1024 + j], __ATOMIC_RELAXED, __HIP_MEMORY_SCOPE_AGENT);
      float gir = enc_gi[(size_t)t * 1536 + j];
      float giz = enc_gi[(size_t)t * 1536 + 512 + j];
      float gin = enc_gi[(size_t)t * 1536 + 1024 + j];
      float r = sigmoid_(gir + (ghr + bhr0));
      float z = sigmoid_(giz + (ghz + bhz0));
      float n = tanhf(gin + r * (ghn + bhn0));
      hn0 = (1.0f - z) * n + z * hs[j];
    }
    {
      int j = tid + 256;
      float ghr = __hip_atomic_load(&ghbuf[par * 1536 + j], __ATOMIC_RELAXED, __HIP_MEMORY_SCOPE_AGENT);
      float ghz = __hip_atomic_load(&ghbuf[par * 1536 + 512 + j], __ATOMIC_RELAXED, __HIP_MEMORY_SCOPE_AGENT);
      float ghn = __hip_atomic_load(&ghbuf[par * 1536 + 1024 + j], __ATOMIC_RELAXED, __HIP_MEMORY_SCOPE_AGENT);
      float gir = enc_gi[(size_t)t * 1536 + j];
      float giz = enc_gi[(size_t)t * 1536 + 512 + j];
      float gin = enc_gi[(size_t)t * 1536 + 1024 + j];
      float r = sigmoid_(gir + (ghr + bhr1));
      float z = sigmoid_(giz + (ghz + bhz1));
      float n = tanhf(gin + r * (ghn + bhn1));
      hn1 = (1.0f - z) * n + z * hs[j];
    }
    hs[tid] = hn0;
    hs[tid + 256] = hn1;
    __syncthreads();
  }
  if (blockIdx.x == 0 && tid < 128)
    *(float4*)&h_T[tid * 4] = *(float4*)&hs[tid * 4];
}

// ---------------------------------------------------------------------------
// Decoder GRU step via bf16 MFMA, 3-split x 6 products.
// Block tile: 128 samples x 64 hidden x 3 gates. 4 waves (2x2).
// LDS: As[3][128][32], Bs[3][192][32] shorts, XOR chunk swizzle (2-way max).
// ---------------------------------------------------------------------------
__global__ __launch_bounds__(256, 2) void dec_gru_mfma(
    const unsigned short* __restrict__ h3_in,   // [3][8192][512]
    const unsigned short* __restrict__ Wr,      // [3][8 jb][192][512]
    const float* __restrict__ giy_k, const float* __restrict__ b_hh,
    const float* __restrict__ W_ih, const float* __restrict__ tgt,
    int tgt_is_x, unsigned short* __restrict__ h3_out) {
  __shared__ unsigned short As[3][128][32];
  __shared__ unsigned short Bs[3][192][32];
  int jb = blockIdx.x;       // 0..7
  int mb = blockIdx.y;       // 0..63
  int tid = threadIdx.x;
  int lane = tid & 63;
  int wave = tid >> 6;
  int wm = wave >> 1, wn = wave & 1;
  int s0 = mb * 128;
  int q = lane >> 4, c = lane & 15;

  f32x4 acc[4][6];
  #pragma unroll
  for (int i = 0; i < 4; i++)
    #pragma unroll
    for (int n = 0; n < 6; n++) acc[i][n] = (f32x4){0.f, 0.f, 0.f, 0.f};

  for (int kb = 0; kb < HIDDEN; kb += 32) {
    // stage A: 3 splits x 128 rows x 32k  (1536 16B-chunks, 6/thread)
    #pragma unroll
    for (int r = 0; r < 6; r++) {
      int a = r * 256 + tid;
      int sp = a >> 9, rem = a & 511;
      int row = rem >> 2, c4 = rem & 3;
      uint4 v = *(const uint4*)(h3_in + (size_t)sp * HPLANE +
                                (size_t)(s0 + row) * 512 + kb + c4 * 8);
      *(uint4*)&As[sp][row][(c4 ^ (row & 3)) * 8] = v;
    }
    // stage B: 3 splits x 192 rows x 32k (2304 chunks, 9/thread)
    #pragma unroll
    for (int r = 0; r < 9; r++) {
      int b = r * 256 + tid;
      int sp = b / 768, rem = b % 768;
      int row = rem >> 2, c4 = rem & 3;
      uint4 v = *(const uint4*)(Wr + (size_t)sp * WPLANE +
                                ((size_t)jb * 192 + row) * 512 + kb + c4 * 8);
      *(uint4*)&Bs[sp][row][(c4 ^ (row & 3)) * 8] = v;
    }
    __syncthreads();

    short8 af[4][3];
    #pragma unroll
    for (int i = 0; i < 4; i++) {
      int m = wm * 64 + i * 16 + c;
      #pragma unroll
      for (int sp = 0; sp < 3; sp++)
        af[i][sp] = *(const short8*)&As[sp][m][(q ^ (c & 3)) * 8];
    }
    #pragma unroll
    for (int nt = 0; nt < 6; nt++) {
      int g = nt >> 1, t = nt & 1;
      int rB = g * 64 + wn * 32 + t * 16 + c;
      short8 bh = *(const short8*)&Bs[0][rB][(q ^ (c & 3)) * 8];
      short8 bm = *(const short8*)&Bs[1][rB][(q ^ (c & 3)) * 8];
      short8 bl = *(const short8*)&Bs[2][rB][(q ^ (c & 3)) * 8];
      #pragma unroll
      for (int i = 0; i < 4; i++) {
        acc[i][nt] = __builtin_amdgcn_mfma_f32_16x16x32_bf16(af[i][0], bh, acc[i][nt], 0, 0, 0);
        acc[i][nt] = __builtin_amdgcn_mfma_f32_16x16x32_bf16(af[i][0], bm, acc[i][nt], 0, 0, 0);
        acc[i][nt] = __builtin_amdgcn_mfma_f32_16x16x32_bf16(af[i][1], bh, acc[i][nt], 0, 0, 0);
        acc[i][nt] = __builtin_amdgcn_mfma_f32_16x16x32_bf16(af[i][0], bl, acc[i][nt], 0, 0, 0);
        acc[i][nt] = __builtin_amdgcn_mfma_f32_16x16x32_bf16(af[i][2], bh, acc[i][nt], 0, 0, 0);
        acc[i][nt] = __builtin_amdgcn_mfma_f32_16x16x32_bf16(af[i][1], bm, acc[i][nt], 0, 0, 0);
      }
    }
    __syncthreads();
  }

  // epilogue: gates + h update + bf16 3-split store
  #pragma unroll
  for (int t = 0; t < 2; t++) {
    int j = jb * 64 + wn * 32 + t * 16 + c;
    float gyr = giy_k[j], gyz = giy_k[512 + j], gyn = giy_k[1024 + j];
    float w0r = W_ih[(size_t)j * 41];
    float w0z = W_ih[(size_t)(512 + j) * 41];
    float w0n = W_ih[(size_t)(1024 + j) * 41];
    float bhr = b_hh[j], bhz = b_hh[512 + j], bhn = b_hh[1024 + j];
    #pragma unroll
    for (int i = 0; i < 4; i++) {
      #pragma unroll
      for (int reg = 0; reg < 4; reg++) {
        int s = s0 + wm * 64 + i * 16 + q * 4 + reg;
        float tg = tgt_is_x ? tgt[HIST - 1] : tgt[s];
        size_t off = (size_t)s * 512 + j;
        float h_old = bf2f_(h3_in[off]) + bf2f_(h3_in[HPLANE + off]) +
                      bf2f_(h3_in[2 * HPLANE + off]);
        float gr = (gyr + w0r * tg) + (acc[i][t][reg] + bhr);
        float gz = (gyz + w0z * tg) + (acc[i][2 + t][reg] + bhz);
        float gn_i = gyn + w0n * tg;
        float gn_h = acc[i][4 + t][reg] + bhn;
        float r_ = sigmoid_(gr);
        float z_ = sigmoid_(gz);
        float n_ = tanhf(gn_i + r_ * gn_h);
        float hn = (1.0f - z_) * n_ + z_ * h_old;
        unsigned short b0 = f2bf_(hn);  float r1 = hn - bf2f_(b0);
        unsigned short b1 = f2bf_(r1);  float r2 = r1 - bf2f_(b1);
        unsigned short b2 = f2bf_(r2);
        h3_out[off] = b0;
        h3_out[HPLANE + off] = b1;
        h3_out[2 * HPLANE + off] = b2;
      }
    }
  }
}

// heads + student-t sampling (h reconstructed from 3 bf16 planes)
__global__ __launch_bounds__(256) void dec_head_kernel(
    const unsigned short* __restrict__ h3, const float* __restrict__ W_df,
    const float* __restrict__ b_df, const float* __restrict__ W_loc,
    const float* __restrict__ b_loc, const float* __restrict__ W_sc,
    const float* __restrict__ b_sc, const float* __restrict__ scale_p,
    float* __restrict__ tgt, float* __restrict__ out, int k) {
  #pragma clang fp contract(off)
  int s = blockIdx.x * 256 + threadIdx.x;
  if (s >= S_N) return;
  size_t base = (size_t)s * 512;
  float adf = 0.f, alo = 0.f, asc = 0.f;
  for (int i = 0; i < HIDDEN / 4; i++) {
    ushort4 p0 = *(const ushort4*)(h3 + base + 4 * i);
    ushort4 p1 = *(const ushort4*)(h3 + HPLANE + base + 4 * i);
    ushort4 p2 = *(const ushort4*)(h3 + 2 * HPLANE + base + 4 * i);
    float x0 = bf2f_(p0.x) + bf2f_(p1.x) + bf2f_(p2.x);
    float x1 = bf2f_(p0.y) + bf2f_(p1.y) + bf2f_(p2.y);
    float x2 = bf2f_(p0.z) + bf2f_(p1.z) + bf2f_(p2.z);
    float x3 = bf2f_(p0.w) + bf2f_(p1.w) + bf2f_(p2.w);
    float4 wd = ((const float4*)W_df)[i];
    float4 wl = ((const float4*)W_loc)[i];
    float4 wsv = ((const float4*)W_sc)[i];
    adf += x0 * wd.x;  adf += x1 * wd.y;  adf += x2 * wd.z;  adf += x3 * wd.w;
    alo += x0 * wl.x;  alo += x1 * wl.y;  alo += x2 * wl.z;  alo += x3 * wl.w;
    asc += x0 * wsv.x; asc += x1 * wsv.y; asc += x2 * wsv.z; asc += x3 * wsv.w;
  }
  float df = 2.0f + softplus_(adf + b_df[0]);
  float loc = alo + b_loc[0];
  float sc = softplus_(asc + b_sc[0]);
  float eps = sample_t_eps_(k, s, df);
  float smp = (loc + sc * eps) * scale_p[0];
  out[(size_t)s * PRED + k] = smp;
  tgt[s] = smp;
}

// ------------------------------- launcher ----------------------------------
extern "C" void kernel_launch(void* const* d_in, const int* in_sizes, int n_in,
                              void* d_out, int out_size, void* d_ws, size_t ws_size,
                              hipStream_t stream) {
  const float* x      = (const float*)d_in[0];
  const float* x_mark = (const float*)d_in[1];
  const float* y_mark = (const float*)d_in[2];
  const float* W_emb  = (const float*)d_in[4];
  const float* b_emb  = (const float*)d_in[5];
  const float* W_ih   = (const float*)d_in[6];
  const float* W_hh   = (const float*)d_in[7];
  const float* b_ih   = (const float*)d_in[8];
  const float* b_hh   = (const float*)d_in[9];
  const float* W_df   = (const float*)d_in[10];
  const float* b_df   = (const float*)d_in[11];
  const float* W_loc  = (const float*)d_in[12];
  const float* b_loc  = (const float*)d_in[13];
  const float* W_sc   = (const float*)d_in[14];
  const float* b_sc   = (const float*)d_in[15];
  float* out = (float*)d_out;

  float* w = (float*)d_ws;
  unsigned short* h3_a = (unsigned short*)(w);                 // 3*8192*512 sh
  unsigned short* h3_b = (unsigned short*)(w + 6291456);       // 3*8192*512 sh
  unsigned short* Wr   = (unsigned short*)(w + 12582912);      // 3*1536*512 sh
  float* enc_gi = w + 13762560;             // 336*1536
  float* giy    = w + 14278656;             // 48*1536
  float* tfe    = w + 14352384;             // 336*40
  float* emb_y  = w + 14365824;             // 48*40
  float* ghbuf  = w + 14367744;             // 2*1536
  float* h_T    = w + 14370816;             // 512
  unsigned short* sT = (unsigned short*)(w + 14371328);  // 3*512 sh = 384 fl
  float* tgt    = w + 14371712;             // 8192
  float* scale_p = w + 14379904;            // 1
  unsigned* syncc = (unsigned*)(w + 14379905);

  prep_kernel<<<1, 256, 0, stream>>>(x, x_mark, y_mark, W_emb, b_emb,
                                     scale_p, tfe, emb_y, syncc);
  enc_gi_kernel<<<HIST, 256, 0, stream>>>(x, tfe, W_ih, b_ih, scale_p, enc_gi);
  giy_kernel<<<PRED, 256, 0, stream>>>(emb_y, W_ih, b_ih, giy);
  wsplit_kernel<<<1536, 256, 0, stream>>>(W_hh, Wr);
  enc_gru_kernel<<<ENC_BLOCKS, 256, 0, stream>>>(enc_gi, W_hh, b_hh, ghbuf,
                                                 syncc, h_T);
  hsplit_kernel<<<1, 256, 0, stream>>>(h_T, sT);
  h3bcast_kernel<<<S_N, 256, 0, stream>>>(sT, h3_a);

  for (int k = 0; k < PRED; k++) {
    const unsigned short* h_in = (k % 2 == 0) ? h3_a : h3_b;
    unsigned short* h_o = (k % 2 == 0) ? h3_b : h3_a;
    dec_gru_mfma<<<dim3(8, 64), 256, 0, stream>>>(
        h_in, Wr, giy + (size_t)k * 1536, b_hh, W_ih,
        (k == 0) ? x : tgt, (k == 0) ? 1 : 0, h_o);
    dec_head_kernel<<<S_N / 256, 256, 0, stream>>>(
        h_o, W_df, b_df, W_loc, b_loc, W_sc, b_sc, scale_p, tgt, out, k);
  }
}

// Round 3
// 6872.099 us; speedup vs baseline: 1.6051x; 1.0985x over previous
//
#include <hip/hip_runtime.h>
#include <cmath>

// ---------------------------------------------------------------------------
// DeepAR sampling on MI355X. Round 3:
//  - decoder grid XCD-swizzled (16 mb x 4 jb rectangle per XCD) to cut A-slab
//    HBM re-fetch 8x (round-2 FETCH_SIZE 227 MB/step was A replicated per XCD)
//  - epilogue h_old captured from the LDS A-tile (no global h3_in re-read)
//  - encoder grid-sync: central atomic counter -> per-block flag array
//    (removes 48-deep serialized atomic chain, ~4.2us -> ~2us per step)
// All arithmetic bit-identical to round 2 (absmax should stay 1.492188).
// ---------------------------------------------------------------------------

#define JAX_PARTITIONABLE 1

#define HIDDEN 512
#define EMB 40
#define HIST 336
#define PRED 48
#define S_N 8192
#define ENC_BLOCKS 48

#define HPLANE (8192 * 512)     // shorts per h split plane
#define WPLANE (1536 * 512)     // shorts per W split plane

typedef __attribute__((ext_vector_type(8))) short short8;
typedef __attribute__((ext_vector_type(4))) float f32x4;

// ------------------------------- threefry ----------------------------------
struct KeyPair { unsigned a, b; };

__device__ __forceinline__ unsigned rotl32_(unsigned v, unsigned s) {
  return (v << s) | (v >> (32u - s));
}

__device__ __forceinline__ KeyPair tf2x32(KeyPair k, unsigned x0, unsigned x1) {
  unsigned ks0 = k.a, ks1 = k.b, ks2 = ks0 ^ ks1 ^ 0x1BD11BDAu;
  x0 += ks0; x1 += ks1;
#define TF_R(r) { x0 += x1; x1 = rotl32_(x1, r); x1 ^= x0; }
  TF_R(13u) TF_R(15u) TF_R(26u) TF_R(6u)  x0 += ks1; x1 += ks2 + 1u;
  TF_R(17u) TF_R(29u) TF_R(16u) TF_R(24u) x0 += ks2; x1 += ks0 + 2u;
  TF_R(13u) TF_R(15u) TF_R(26u) TF_R(6u)  x0 += ks0; x1 += ks1 + 3u;
  TF_R(17u) TF_R(29u) TF_R(16u) TF_R(24u) x0 += ks1; x1 += ks2 + 4u;
  TF_R(13u) TF_R(15u) TF_R(26u) TF_R(6u)  x0 += ks2; x1 += ks0 + 5u;
#undef TF_R
  KeyPair r; r.a = x0; r.b = x1; return r;
}

__device__ __forceinline__ void split2_(KeyPair key, KeyPair& r0, KeyPair& r1) {
#if JAX_PARTITIONABLE
  r0 = tf2x32(key, 0u, 0u);
  r1 = tf2x32(key, 0u, 1u);
#else
  KeyPair p0 = tf2x32(key, 0u, 2u);
  KeyPair p1 = tf2x32(key, 1u, 3u);
  r0.a = p0.a; r0.b = p1.a;
  r1.a = p0.b; r1.b = p1.b;
#endif
}

__device__ __forceinline__ void split3_(KeyPair key, KeyPair& r0, KeyPair& r1, KeyPair& r2) {
#if JAX_PARTITIONABLE
  r0 = tf2x32(key, 0u, 0u);
  r1 = tf2x32(key, 0u, 1u);
  r2 = tf2x32(key, 0u, 2u);
#else
  KeyPair p0 = tf2x32(key, 0u, 3u);
  KeyPair p1 = tf2x32(key, 1u, 4u);
  KeyPair p2 = tf2x32(key, 2u, 5u);
  r0.a = p0.a; r0.b = p1.a;
  r1.a = p2.a; r1.b = p0.b;
  r2.a = p1.b; r2.b = p2.b;
#endif
}

__device__ __forceinline__ unsigned scalar_bits_(KeyPair key) {
#if JAX_PARTITIONABLE
  KeyPair p = tf2x32(key, 0u, 0u);
  return p.a ^ p.b;
#else
  return tf2x32(key, 0u, 0u).a;
#endif
}

__device__ __forceinline__ unsigned batch_bits_8192_(KeyPair key, int s) {
#if JAX_PARTITIONABLE
  KeyPair p = tf2x32(key, 0u, (unsigned)s);
  return p.a ^ p.b;
#else
  if (s < 4096) return tf2x32(key, (unsigned)s, (unsigned)(4096 + s)).a;
  return tf2x32(key, (unsigned)(s - 4096), (unsigned)s).b;
#endif
}

__device__ __forceinline__ KeyPair subkey_of_8192_(KeyPair key, int s) {
#if JAX_PARTITIONABLE
  return tf2x32(key, 0u, (unsigned)s);
#else
  KeyPair r;
  if (s < 4096) {
    r.a = tf2x32(key, (unsigned)(2 * s),     (unsigned)(8192 + 2 * s)).a;
    r.b = tf2x32(key, (unsigned)(2 * s + 1), (unsigned)(8192 + 2 * s + 1)).a;
  } else {
    int m = 2 * s - 8192;
    r.a = tf2x32(key, (unsigned)m,       (unsigned)(m + 8192)).b;
    r.b = tf2x32(key, (unsigned)(m + 1), (unsigned)(m + 1 + 8192)).b;
  }
  return r;
#endif
}

// ------------------------- fp32 numerics (XLA-matched) ---------------------
__device__ __forceinline__ float acc_logf_(float x) {
  return (float)log((double)x);
}
__device__ __forceinline__ float acc_expf_(float x) {
  return (float)exp((double)x);
}

__device__ __forceinline__ float bits_to_uniform01_(unsigned bits) {
  return __uint_as_float((bits >> 9) | 0x3F800000u) - 1.0f;
}

__device__ __forceinline__ float xla_log1pf_(float t) {
  #pragma clang fp contract(off)
  float small_ = (1.0f + (-0.5f) * t) * t;
  float large_ = acc_logf_(t + 1.0f);
  return (fabsf(t) < 1e-4f) ? small_ : large_;
}

__device__ float xla_erfinv_(float x) {
  #pragma clang fp contract(off)
  float w = -xla_log1pf_(-(x * x));
  float p;
  if (w < 5.0f) {
    float ww = w - 2.5f;
    p = 2.81022636e-08f;
    p = 3.43273939e-07f + p * ww;
    p = -3.5233877e-06f + p * ww;
    p = -4.39150654e-06f + p * ww;
    p = 0.00021858087f + p * ww;
    p = -0.00125372503f + p * ww;
    p = -0.00417768164f + p * ww;
    p = 0.246640727f + p * ww;
    p = 1.50140941f + p * ww;
  } else {
    float ww = sqrtf(w) - 3.0f;
    p = -0.000200214257f;
    p = 0.000100950558f + p * ww;
    p = 0.00134934322f + p * ww;
    p = -0.00367342844f + p * ww;
    p = 0.00573950773f + p * ww;
    p = -0.0076224613f + p * ww;
    p = 0.00943887047f + p * ww;
    p = 1.00167406f + p * ww;
    p = 2.83297682f + p * ww;
  }
  return p * x;
}

__device__ float bits_to_normal_(unsigned bits) {
  #pragma clang fp contract(off)
  const float lo = __uint_as_float(0xBF7FFFFFu);
  float f = bits_to_uniform01_(bits);
  float u = f * 2.0f + lo;
  u = fmaxf(lo, u);
  return __uint_as_float(0x3FB504F3u) * xla_erfinv_(u);
}

__device__ __forceinline__ float softplus_(float x) {
  #pragma clang fp contract(off)
  float amax = fmaxf(x, 0.0f);
  float e = acc_expf_(-fabsf(x));
  return amax + xla_log1pf_(e);
}

__device__ __forceinline__ float sigmoid_(float v) { return 1.0f / (1.0f + expf(-v)); }

// bf16 round-to-nearest-even split helpers
__device__ __forceinline__ unsigned short f2bf_(float f) {
  unsigned u = __float_as_uint(f);
  unsigned r = (u + 0x7FFFu + ((u >> 16) & 1u)) >> 16;
  return (unsigned short)r;
}
__device__ __forceinline__ float bf2f_(unsigned short b) {
  return __uint_as_float(((unsigned)b) << 16);
}

// ------------------------- gamma / student-t sampler -----------------------
__device__ float gamma_sample_(KeyPair gkey, float alpha) {
  #pragma clang fp contract(off)
  const float third = 0.33333334f;
  float d = alpha - third;
  float c = third / sqrtf(d);
  KeyPair key, boost_sub;
  split2_(gkey, key, boost_sub);
  (void)boost_sub;
  float X = 0.0f, V = 1.0f, U = 2.0f;
  for (int guard = 0; guard < 1024; guard++) {
    float X2 = X * X;
    float sq = 1.0f - 0.0331f * (X2 * X2);
    bool cont = false;
    if (U >= sq) {
      float lhs = acc_logf_(U);
      float rhs = (X * 0.5f) + (d * ((1.0f - V) + acc_logf_(V)));
      cont = (lhs >= rhs);
    }
    if (!cont) break;
    KeyPair nkey, xkey, Ukey;
    split3_(key, nkey, xkey, Ukey);
    key = nkey;
    float x, v;
    KeyPair kk = xkey;
    do {
      KeyPair knew, sub;
      split2_(kk, knew, sub);
      kk = knew;
      x = bits_to_normal_(scalar_bits_(sub));
      v = 1.0f + x * c;
    } while (v <= 0.0f);
    X = x * x;
    V = (v * v) * v;
    U = bits_to_uniform01_(scalar_bits_(Ukey));
  }
  return d * V;
}

__device__ float sample_t_eps_(int k, int s, float df) {
  #pragma clang fp contract(off)
  KeyPair base; base.a = 0u; base.b = 42u;
  KeyPair tkey = tf2x32(base, 0u, (unsigned)k);
  KeyPair key_n, key_g;
  split2_(tkey, key_n, key_g);
  float n = bits_to_normal_(batch_bits_8192_(key_n, s));
  KeyPair gkey = subkey_of_8192_(key_g, s);
  float half_df = df * 0.5f;
  float g = gamma_sample_(gkey, half_df);
  return n * sqrtf(half_df / g);
}

// ------------------------------- kernels -----------------------------------

__global__ __launch_bounds__(256) void prep_kernel(
    const float* __restrict__ x, const float* __restrict__ x_mark,
    const float* __restrict__ y_mark, const float* __restrict__ W_emb,
    const float* __restrict__ b_emb, float* __restrict__ scale_p,
    float* __restrict__ tfe, float* __restrict__ emb_y,
    unsigned* __restrict__ flags) {
  int tid = threadIdx.x;
  if (tid == 0) {
    float s = 0.0f;
    for (int t = 0; t < HIST; t++) s += fabsf(x[t]);
    float m = s / 336.0f;
    scale_p[0] = fmaxf(m, 1e-5f);
  }
  // zero the encoder barrier flags (48 blocks x 16-int stride)
  for (int i = tid; i < ENC_BLOCKS * 16; i += 256) flags[i] = 0u;
  for (int idx = tid; idx < HIST * EMB; idx += 256) {
    int t = idx / EMB, e = idx % EMB;
    float a = b_emb[e];
    for (int f = 0; f < 4; f++) a += x_mark[t * 4 + f] * W_emb[e * 4 + f];
    tfe[idx] = a;
  }
  for (int idx = tid; idx < PRED * EMB; idx += 256) {
    int kk = idx / EMB, e = idx % EMB;
    float a = b_emb[e];
    for (int f = 0; f < 4; f++) a += y_mark[kk * 4 + f] * W_emb[e * 4 + f];
    emb_y[idx] = a;
  }
}

__global__ __launch_bounds__(256) void enc_gi_kernel(
    const float* __restrict__ x, const float* __restrict__ tfe,
    const float* __restrict__ W_ih, const float* __restrict__ b_ih,
    const float* __restrict__ scale_p, float* __restrict__ enc_gi) {
  __shared__ float fe[EMB];
  __shared__ float xs_s;
  int t = blockIdx.x;
  int tid = threadIdx.x;
  if (tid < EMB) fe[tid] = tfe[t * EMB + tid];
  if (tid == 0) xs_s = x[t] / scale_p[0];
  __syncthreads();
  float xs = xs_s;
  for (int r = tid; r < 3 * HIDDEN; r += 256) {
    const float* wr = W_ih + (size_t)r * 41;
    float a = b_ih[r] + wr[0] * xs;
    #pragma unroll
    for (int e = 0; e < EMB; e++) a += wr[1 + e] * fe[e];
    enc_gi[(size_t)t * 1536 + r] = a;
  }
}

__global__ __launch_bounds__(256) void giy_kernel(
    const float* __restrict__ emb_y, const float* __restrict__ W_ih,
    const float* __restrict__ b_ih, float* __restrict__ giy) {
  __shared__ float fe[EMB];
  int k = blockIdx.x;
  int tid = threadIdx.x;
  if (tid < EMB) fe[tid] = emb_y[k * EMB + tid];
  __syncthreads();
  for (int r = tid; r < 3 * HIDDEN; r += 256) {
    const float* wr = W_ih + (size_t)r * 41;
    float a = b_ih[r];
    #pragma unroll
    for (int e = 0; e < EMB; e++) a += wr[1 + e] * fe[e];
    giy[(size_t)k * 1536 + r] = a;
  }
}

// W_hh -> 3 bf16 split planes, rearranged per jb-slab: Wr[sp][jb][g*64+jl][k]
__global__ __launch_bounds__(256) void wsplit_kernel(
    const float* __restrict__ W_hh, unsigned short* __restrict__ Wr) {
  int row = blockIdx.x;                 // 0..1535
  int g = row >> 9;
  int jg = row & 511;
  int jb = jg >> 6, jl = jg & 63;
  size_t dst = ((size_t)jb * 192 + g * 64 + jl) * 512;
  for (int k = threadIdx.x; k < 512; k += 256) {
    float w = W_hh[(size_t)row * 512 + k];
    unsigned short b0 = f2bf_(w);  float r1 = w - bf2f_(b0);
    unsigned short b1 = f2bf_(r1); float r2 = r1 - bf2f_(b1);
    unsigned short b2 = f2bf_(r2);
    Wr[dst + k] = b0;
    Wr[WPLANE + dst + k] = b1;
    Wr[2 * WPLANE + dst + k] = b2;
  }
}

// split h_T (512) into sT[3][512]
__global__ __launch_bounds__(256) void hsplit_kernel(
    const float* __restrict__ h_T, unsigned short* __restrict__ sT) {
  int i = threadIdx.x;
  for (int j = i; j < 512; j += 256) {
    float v = h_T[j];
    unsigned short b0 = f2bf_(v);  float r1 = v - bf2f_(b0);
    unsigned short b1 = f2bf_(r1); float r2 = r1 - bf2f_(b1);
    unsigned short b2 = f2bf_(r2);
    sT[j] = b0; sT[512 + j] = b1; sT[1024 + j] = b2;
  }
}

// broadcast sT rows into h3[3][8192][512]
__global__ __launch_bounds__(256) void h3bcast_kernel(
    const unsigned short* __restrict__ sT, unsigned short* __restrict__ h3) {
  int row = blockIdx.x;
  int tid = threadIdx.x;
  if (tid < 192) {
    int sp = tid >> 6, c = tid & 63;
    ((uint4*)(h3 + (size_t)sp * HPLANE + (size_t)row * 512))[c] =
        ((const uint4*)(sT + sp * 512))[c];
  }
}

// persistent encoder GRU; flag-array grid barrier (uncontended release store
// per block + wave-parallel acquire polls, replaces serialized atomic chain)
__global__ __launch_bounds__(256) void enc_gru_kernel(
    const float* __restrict__ enc_gi, const float* __restrict__ W_hh,
    const float* __restrict__ b_hh, float* __restrict__ ghbuf,
    unsigned* __restrict__ flags, float* __restrict__ h_T) {
  __shared__ __align__(16) float hs[HIDDEN];
  int tid = threadIdx.x;
  int gtid = blockIdx.x * 256 + tid;
  int row = gtid >> 3;
  int sub = gtid & 7;

  float w[64];
  const float* wp = W_hh + (size_t)row * HIDDEN + sub * 64;
  #pragma unroll
  for (int i = 0; i < 16; i++) {
    float4 v = *(const float4*)(wp + 4 * i);
    w[4 * i + 0] = v.x; w[4 * i + 1] = v.y; w[4 * i + 2] = v.z; w[4 * i + 3] = v.w;
  }
  if (tid < 128) *(float4*)&hs[tid * 4] = make_float4(0.f, 0.f, 0.f, 0.f);
  float bhr0 = b_hh[tid],       bhz0 = b_hh[512 + tid],  bhn0 = b_hh[1024 + tid];
  float bhr1 = b_hh[256 + tid], bhz1 = b_hh[768 + tid],  bhn1 = b_hh[1280 + tid];
  __syncthreads();

  for (int t = 0; t < HIST; t++) {
    float p = 0.0f;
    const float4* hv = (const float4*)&hs[sub * 64];
    #pragma unroll
    for (int i = 0; i < 16; i++) {
      float4 v = hv[i];
      p += w[4 * i + 0] * v.x + w[4 * i + 1] * v.y +
           w[4 * i + 2] * v.z + w[4 * i + 3] * v.w;
    }
    p += __shfl_xor(p, 1, 64);
    p += __shfl_xor(p, 2, 64);
    p += __shfl_xor(p, 4, 64);
    int par = t & 1;
    if (sub == 0)
      __hip_atomic_store(&ghbuf[par * 1536 + row], p, __ATOMIC_RELAXED,
                         __HIP_MEMORY_SCOPE_AGENT);
    // flag-array grid barrier
    __syncthreads();   // drains vmcnt -> partial stores agent-visible
    if (tid == 0)
      __hip_atomic_store(&flags[blockIdx.x * 16], (unsigned)(t + 1),
                         __ATOMIC_RELEASE, __HIP_MEMORY_SCOPE_AGENT);
    if (tid < ENC_BLOCKS) {
      while (__hip_atomic_load(&flags[tid * 16], __ATOMIC_ACQUIRE,
                               __HIP_MEMORY_SCOPE_AGENT) < (unsigned)(t + 1))
        __builtin_amdgcn_s_sleep(1);
    }
    __syncthreads();
    float hn0, hn1;
    {
      int j = tid;
      float ghr = __hip_atomic_load(&ghbuf[par * 1536 + j], __ATOMIC_RELAXED, __HIP_MEMORY_SCOPE_AGENT);
      float ghz = __hip_atomic_load(&ghbuf[par * 1536 + 512 + j], __ATOMIC_RELAXED, __HIP_MEMORY_SCOPE_AGENT);
      float ghn = __hip_atomic_load(&ghbuf[par * 1536 + 1024 + j], __ATOMIC_RELAXED, __HIP_MEMORY_SCOPE_AGENT);
      float gir = enc_gi[(size_t)t * 1536 + j];
      float giz = enc_gi[(size_t)t * 1536 + 512 + j];
      float gin = enc_gi[(size_t)t * 1536 + 1024 + j];
      float r = sigmoid_(gir + (ghr + bhr0));
      float z = sigmoid_(giz + (ghz + bhz0));
      float n = tanhf(gin + r * (ghn + bhn0));
      hn0 = (1.0f - z) * n + z * hs[j];
    }
    {
      int j = tid + 256;
      float ghr = __hip_atomic_load(&ghbuf[par * 1536 + j], __ATOMIC_RELAXED, __HIP_MEMORY_SCOPE_AGENT);
      float ghz = __hip_atomic_load(&ghbuf[par * 1536 + 512 + j], __ATOMIC_RELAXED, __HIP_MEMORY_SCOPE_AGENT);
      float ghn = __hip_atomic_load(&ghbuf[par * 1536 + 1024 + j], __ATOMIC_RELAXED, __HIP_MEMORY_SCOPE_AGENT);
      float gir = enc_gi[(size_t)t * 1536 + j];
      float giz = enc_gi[(size_t)t * 1536 + 512 + j];
      float gin = enc_gi[(size_t)t * 1536 + 1024 + j];
      float r = sigmoid_(gir + (ghr + bhr1));
      float z = sigmoid_(giz + (ghz + bhz1));
      float n = tanhf(gin + r * (ghn + bhn1));
      hn1 = (1.0f - z) * n + z * hs[j];
    }
    hs[tid] = hn0;
    hs[tid + 256] = hn1;
    __syncthreads();
  }
  if (blockIdx.x == 0 && tid < 128)
    *(float4*)&h_T[tid * 4] = *(float4*)&hs[tid * 4];
}

// ---------------------------------------------------------------------------
// Decoder GRU step via bf16 MFMA, 3-split x 6 products.
// 1-D grid of 512, XCD-swizzled: xcd = b&7 owns a 16 mb x 4 jb rectangle
// (per-XCD compulsory fetch ~11 MB instead of A replicated across XCDs).
// Block tile: 128 samples x 64 hidden x 3 gates. 4 waves (2x2).
// Epilogue h_old is captured from the LDS A-tile (kb == jb*64 + wn*32).
// ---------------------------------------------------------------------------
__global__ __launch_bounds__(256, 2) void dec_gru_mfma(
    const unsigned short* __restrict__ h3_in,   // [3][8192][512]
    const unsigned short* __restrict__ Wr,      // [3][8 jb][192][512]
    const float* __restrict__ giy_k, const float* __restrict__ b_hh,
    const float* __restrict__ W_ih, const float* __restrict__ tgt,
    int tgt_is_x, unsigned short* __restrict__ h3_out) {
  __shared__ unsigned short As[3][128][32];
  __shared__ unsigned short Bs[3][192][32];
  int b_ = blockIdx.x;
  int xcd = b_ & 7, slot = b_ >> 3;
  int g_ = xcd & 3, h_ = xcd >> 2;
  int mb = g_ * 16 + (slot & 15);     // 0..63
  int jb = h_ * 4 + (slot >> 4);      // 0..7
  int tid = threadIdx.x;
  int lane = tid & 63;
  int wave = tid >> 6;
  int wm = wave >> 1, wn = wave & 1;
  int s0 = mb * 128;
  int q = lane >> 4, c = lane & 15;

  f32x4 acc[4][6];
  #pragma unroll
  for (int i = 0; i < 4; i++)
    #pragma unroll
    for (int n = 0; n < 6; n++) acc[i][n] = (f32x4){0.f, 0.f, 0.f, 0.f};

  float hold[2][4][4];
  #pragma unroll
  for (int t = 0; t < 2; t++)
    #pragma unroll
    for (int i = 0; i < 4; i++)
      #pragma unroll
      for (int r = 0; r < 4; r++) hold[t][i][r] = 0.f;

  int kb_cap = jb * 64 + wn * 32;   // k-block holding this wave's j-columns

  for (int kb = 0; kb < HIDDEN; kb += 32) {
    // stage A: 3 splits x 128 rows x 32k  (1536 16B-chunks, 6/thread)
    #pragma unroll
    for (int r = 0; r < 6; r++) {
      int a = r * 256 + tid;
      int sp = a >> 9, rem = a & 511;
      int row = rem >> 2, c4 = rem & 3;
      uint4 v = *(const uint4*)(h3_in + (size_t)sp * HPLANE +
                                (size_t)(s0 + row) * 512 + kb + c4 * 8);
      *(uint4*)&As[sp][row][(c4 ^ (row & 3)) * 8] = v;
    }
    // stage B: 3 splits x 192 rows x 32k (2304 chunks, 9/thread)
    #pragma unroll
    for (int r = 0; r < 9; r++) {
      int b = r * 256 + tid;
      int sp = b / 768, rem = b % 768;
      int row = rem >> 2, c4 = rem & 3;
      uint4 v = *(const uint4*)(Wr + (size_t)sp * WPLANE +
                                ((size_t)jb * 192 + row) * 512 + kb + c4 * 8);
      *(uint4*)&Bs[sp][row][(c4 ^ (row & 3)) * 8] = v;
    }
    __syncthreads();

    // capture h_old for the epilogue while it sits in LDS
    if (kb == kb_cap) {
      #pragma unroll
      for (int t = 0; t < 2; t++)
        #pragma unroll
        for (int i = 0; i < 4; i++)
          #pragma unroll
          for (int reg = 0; reg < 4; reg++) {
            int m = wm * 64 + i * 16 + q * 4 + reg;
            int cc = t * 16 + c;
            int idx = (((cc >> 3) ^ (m & 3)) << 3) + (cc & 7);
            hold[t][i][reg] = bf2f_(As[0][m][idx]) + bf2f_(As[1][m][idx]) +
                              bf2f_(As[2][m][idx]);
          }
    }

    short8 af[4][3];
    #pragma unroll
    for (int i = 0; i < 4; i++) {
      int m = wm * 64 + i * 16 + c;
      #pragma unroll
      for (int sp = 0; sp < 3; sp++)
        af[i][sp] = *(const short8*)&As[sp][m][(q ^ (c & 3)) * 8];
    }
    #pragma unroll
    for (int nt = 0; nt < 6; nt++) {
      int g = nt >> 1, t = nt & 1;
      int rB = g * 64 + wn * 32 + t * 16 + c;
      short8 bh = *(const short8*)&Bs[0][rB][(q ^ (c & 3)) * 8];
      short8 bm = *(const short8*)&Bs[1][rB][(q ^ (c & 3)) * 8];
      short8 bl = *(const short8*)&Bs[2][rB][(q ^ (c & 3)) * 8];
      #pragma unroll
      for (int i = 0; i < 4; i++) {
        acc[i][nt] = __builtin_amdgcn_mfma_f32_16x16x32_bf16(af[i][0], bh, acc[i][nt], 0, 0, 0);
        acc[i][nt] = __builtin_amdgcn_mfma_f32_16x16x32_bf16(af[i][0], bm, acc[i][nt], 0, 0, 0);
        acc[i][nt] = __builtin_amdgcn_mfma_f32_16x16x32_bf16(af[i][1], bh, acc[i][nt], 0, 0, 0);
        acc[i][nt] = __builtin_amdgcn_mfma_f32_16x16x32_bf16(af[i][0], bl, acc[i][nt], 0, 0, 0);
        acc[i][nt] = __builtin_amdgcn_mfma_f32_16x16x32_bf16(af[i][2], bh, acc[i][nt], 0, 0, 0);
        acc[i][nt] = __builtin_amdgcn_mfma_f32_16x16x32_bf16(af[i][1], bm, acc[i][nt], 0, 0, 0);
      }
    }
    __syncthreads();
  }

  // epilogue: gates + h update + bf16 3-split store
  #pragma unroll
  for (int t = 0; t < 2; t++) {
    int j = jb * 64 + wn * 32 + t * 16 + c;
    float gyr = giy_k[j], gyz = giy_k[512 + j], gyn = giy_k[1024 + j];
    float w0r = W_ih[(size_t)j * 41];
    float w0z = W_ih[(size_t)(512 + j) * 41];
    float w0n = W_ih[(size_t)(1024 + j) * 41];
    float bhr = b_hh[j], bhz = b_hh[512 + j], bhn = b_hh[1024 + j];
    #pragma unroll
    for (int i = 0; i < 4; i++) {
      #pragma unroll
      for (int reg = 0; reg < 4; reg++) {
        int s = s0 + wm * 64 + i * 16 + q * 4 + reg;
        float tg = tgt_is_x ? tgt[HIST - 1] : tgt[s];
        size_t off = (size_t)s * 512 + j;
        float h_old = hold[t][i][reg];
        float gr = (gyr + w0r * tg) + (acc[i][t][reg] + bhr);
        float gz = (gyz + w0z * tg) + (acc[i][2 + t][reg] + bhz);
        float gn_i = gyn + w0n * tg;
        float gn_h = acc[i][4 + t][reg] + bhn;
        float r_ = sigmoid_(gr);
        float z_ = sigmoid_(gz);
        float n_ = tanhf(gn_i + r_ * gn_h);
        float hn = (1.0f - z_) * n_ + z_ * h_old;
        unsigned short b0 = f2bf_(hn);  float r1 = hn - bf2f_(b0);
        unsigned short b1 = f2bf_(r1);  float r2 = r1 - bf2f_(b1);
        unsigned short b2 = f2bf_(r2);
        h3_out[off] = b0;
        h3_out[HPLANE + off] = b1;
        h3_out[2 * HPLANE + off] = b2;
      }
    }
  }
}

// heads + student-t sampling (h reconstructed from 3 bf16 planes)
__global__ __launch_bounds__(256) void dec_head_kernel(
    const unsigned short* __restrict__ h3, const float* __restrict__ W_df,
    const float* __restrict__ b_df, const float* __restrict__ W_loc,
    const float* __restrict__ b_loc, const float* __restrict__ W_sc,
    const float* __restrict__ b_sc, const float* __restrict__ scale_p,
    float* __restrict__ tgt, float* __restrict__ out, int k) {
  #pragma clang fp contract(off)
  int s = blockIdx.x * 256 + threadIdx.x;
  if (s >= S_N) return;
  size_t base = (size_t)s * 512;
  float adf = 0.f, alo = 0.f, asc = 0.f;
  for (int i = 0; i < HIDDEN / 4; i++) {
    ushort4 p0 = *(const ushort4*)(h3 + base + 4 * i);
    ushort4 p1 = *(const ushort4*)(h3 + HPLANE + base + 4 * i);
    ushort4 p2 = *(const ushort4*)(h3 + 2 * HPLANE + base + 4 * i);
    float x0 = bf2f_(p0.x) + bf2f_(p1.x) + bf2f_(p2.x);
    float x1 = bf2f_(p0.y) + bf2f_(p1.y) + bf2f_(p2.y);
    float x2 = bf2f_(p0.z) + bf2f_(p1.z) + bf2f_(p2.z);
    float x3 = bf2f_(p0.w) + bf2f_(p1.w) + bf2f_(p2.w);
    float4 wd = ((const float4*)W_df)[i];
    float4 wl = ((const float4*)W_loc)[i];
    float4 wsv = ((const float4*)W_sc)[i];
    adf += x0 * wd.x;  adf += x1 * wd.y;  adf += x2 * wd.z;  adf += x3 * wd.w;
    alo += x0 * wl.x;  alo += x1 * wl.y;  alo += x2 * wl.z;  alo += x3 * wl.w;
    asc += x0 * wsv.x; asc += x1 * wsv.y; asc += x2 * wsv.z; asc += x3 * wsv.w;
  }
  float df = 2.0f + softplus_(adf + b_df[0]);
  float loc = alo + b_loc[0];
  float sc = softplus_(asc + b_sc[0]);
  float eps = sample_t_eps_(k, s, df);
  float smp = (loc + sc * eps) * scale_p[0];
  out[(size_t)s * PRED + k] = smp;
  tgt[s] = smp;
}

// ------------------------------- launcher ----------------------------------
extern "C" void kernel_launch(void* const* d_in, const int* in_sizes, int n_in,
                              void* d_out, int out_size, void* d_ws, size_t ws_size,
                              hipStream_t stream) {
  const float* x      = (const float*)d_in[0];
  const float* x_mark = (const float*)d_in[1];
  const float* y_mark = (const float*)d_in[2];
  const float* W_emb  = (const float*)d_in[4];
  const float* b_emb  = (const float*)d_in[5];
  const float* W_ih   = (const float*)d_in[6];
  const float* W_hh   = (const float*)d_in[7];
  const float* b_ih   = (const float*)d_in[8];
  const float* b_hh   = (const float*)d_in[9];
  const float* W_df   = (const float*)d_in[10];
  const float* b_df   = (const float*)d_in[11];
  const float* W_loc  = (const float*)d_in[12];
  const float* b_loc  = (const float*)d_in[13];
  const float* W_sc   = (const float*)d_in[14];
  const float* b_sc   = (const float*)d_in[15];
  float* out = (float*)d_out;

  float* w = (float*)d_ws;
  unsigned short* h3_a = (unsigned short*)(w);                 // 3*8192*512 sh
  unsigned short* h3_b = (unsigned short*)(w + 6291456);       // 3*8192*512 sh
  unsigned short* Wr   = (unsigned short*)(w + 12582912);      // 3*1536*512 sh
  float* enc_gi = w + 13762560;             // 336*1536
  float* giy    = w + 14278656;             // 48*1536
  float* tfe    = w + 14352384;             // 336*40
  float* emb_y  = w + 14365824;             // 48*40
  float* ghbuf  = w + 14367744;             // 2*1536
  float* h_T    = w + 14370816;             // 512
  unsigned short* sT = (unsigned short*)(w + 14371328);  // 3*512 sh
  float* tgt    = w + 14371712;             // 8192
  float* scale_p = w + 14379904;            // 1
  unsigned* flags = (unsigned*)(w + 14379908);  // 48*16 ints (16B aligned)

  prep_kernel<<<1, 256, 0, stream>>>(x, x_mark, y_mark, W_emb, b_emb,
                                     scale_p, tfe, emb_y, flags);
  enc_gi_kernel<<<HIST, 256, 0, stream>>>(x, tfe, W_ih, b_ih, scale_p, enc_gi);
  giy_kernel<<<PRED, 256, 0, stream>>>(emb_y, W_ih, b_ih, giy);
  wsplit_kernel<<<1536, 256, 0, stream>>>(W_hh, Wr);
  enc_gru_kernel<<<ENC_BLOCKS, 256, 0, stream>>>(enc_gi, W_hh, b_hh, ghbuf,
                                                 flags, h_T);
  hsplit_kernel<<<1, 256, 0, stream>>>(h_T, sT);
  h3bcast_kernel<<<S_N, 256, 0, stream>>>(sT, h3_a);

  for (int k = 0; k < PRED; k++) {
    const unsigned short* h_in = (k % 2 == 0) ? h3_a : h3_b;
    unsigned short* h_o = (k % 2 == 0) ? h3_b : h3_a;
    dec_gru_mfma<<<512, 256, 0, stream>>>(
        h_in, Wr, giy + (size_t)k * 1536, b_hh, W_ih,
        (k == 0) ? x : tgt, (k == 0) ? 1 : 0, h_o);
    dec_head_kernel<<<S_N / 256, 256, 0, stream>>>(
        h_o, W_df, b_df, W_loc, b_loc, W_sc, b_sc, scale_p, tgt, out, k);
  }
}

// Round 4
// 6852.978 us; speedup vs baseline: 1.6096x; 1.0028x over previous
//
#include <hip/hip_runtime.h>
#include <cmath>

// ---------------------------------------------------------------------------
// DeepAR sampling on MI355X. Round 4:
//  - encoder grid-sync -> single-round-trip tagged 64-bit gh words
//    ((t+1)<<32 | f32bits, relaxed agent atomics, parity double-buffer);
//    removes flag round trip + fences (was 2 serialized cross-XCD trips).
//  - dec_head: 32x256 -> 128x64 blocks (4x CU coverage for its 24 MB h3
//    read) + uint4 loads; accumulation order preserved -> bit-identical.
//  - decoder GEMM (dec_gru_mfma) unchanged from round 3.
// ---------------------------------------------------------------------------

#define JAX_PARTITIONABLE 1

#define HIDDEN 512
#define EMB 40
#define HIST 336
#define PRED 48
#define S_N 8192
#define ENC_BLOCKS 48

#define HPLANE (8192 * 512)     // shorts per h split plane
#define WPLANE (1536 * 512)     // shorts per W split plane

typedef __attribute__((ext_vector_type(8))) short short8;
typedef __attribute__((ext_vector_type(4))) float f32x4;
typedef unsigned long long ull;

// ------------------------------- threefry ----------------------------------
struct KeyPair { unsigned a, b; };

__device__ __forceinline__ unsigned rotl32_(unsigned v, unsigned s) {
  return (v << s) | (v >> (32u - s));
}

__device__ __forceinline__ KeyPair tf2x32(KeyPair k, unsigned x0, unsigned x1) {
  unsigned ks0 = k.a, ks1 = k.b, ks2 = ks0 ^ ks1 ^ 0x1BD11BDAu;
  x0 += ks0; x1 += ks1;
#define TF_R(r) { x0 += x1; x1 = rotl32_(x1, r); x1 ^= x0; }
  TF_R(13u) TF_R(15u) TF_R(26u) TF_R(6u)  x0 += ks1; x1 += ks2 + 1u;
  TF_R(17u) TF_R(29u) TF_R(16u) TF_R(24u) x0 += ks2; x1 += ks0 + 2u;
  TF_R(13u) TF_R(15u) TF_R(26u) TF_R(6u)  x0 += ks0; x1 += ks1 + 3u;
  TF_R(17u) TF_R(29u) TF_R(16u) TF_R(24u) x0 += ks1; x1 += ks2 + 4u;
  TF_R(13u) TF_R(15u) TF_R(26u) TF_R(6u)  x0 += ks2; x1 += ks0 + 5u;
#undef TF_R
  KeyPair r; r.a = x0; r.b = x1; return r;
}

__device__ __forceinline__ void split2_(KeyPair key, KeyPair& r0, KeyPair& r1) {
#if JAX_PARTITIONABLE
  r0 = tf2x32(key, 0u, 0u);
  r1 = tf2x32(key, 0u, 1u);
#else
  KeyPair p0 = tf2x32(key, 0u, 2u);
  KeyPair p1 = tf2x32(key, 1u, 3u);
  r0.a = p0.a; r0.b = p1.a;
  r1.a = p0.b; r1.b = p1.b;
#endif
}

__device__ __forceinline__ void split3_(KeyPair key, KeyPair& r0, KeyPair& r1, KeyPair& r2) {
#if JAX_PARTITIONABLE
  r0 = tf2x32(key, 0u, 0u);
  r1 = tf2x32(key, 0u, 1u);
  r2 = tf2x32(key, 0u, 2u);
#else
  KeyPair p0 = tf2x32(key, 0u, 3u);
  KeyPair p1 = tf2x32(key, 1u, 4u);
  KeyPair p2 = tf2x32(key, 2u, 5u);
  r0.a = p0.a; r0.b = p1.a;
  r1.a = p2.a; r1.b = p0.b;
  r2.a = p1.b; r2.b = p2.b;
#endif
}

__device__ __forceinline__ unsigned scalar_bits_(KeyPair key) {
#if JAX_PARTITIONABLE
  KeyPair p = tf2x32(key, 0u, 0u);
  return p.a ^ p.b;
#else
  return tf2x32(key, 0u, 0u).a;
#endif
}

__device__ __forceinline__ unsigned batch_bits_8192_(KeyPair key, int s) {
#if JAX_PARTITIONABLE
  KeyPair p = tf2x32(key, 0u, (unsigned)s);
  return p.a ^ p.b;
#else
  if (s < 4096) return tf2x32(key, (unsigned)s, (unsigned)(4096 + s)).a;
  return tf2x32(key, (unsigned)(s - 4096), (unsigned)s).b;
#endif
}

__device__ __forceinline__ KeyPair subkey_of_8192_(KeyPair key, int s) {
#if JAX_PARTITIONABLE
  return tf2x32(key, 0u, (unsigned)s);
#else
  KeyPair r;
  if (s < 4096) {
    r.a = tf2x32(key, (unsigned)(2 * s),     (unsigned)(8192 + 2 * s)).a;
    r.b = tf2x32(key, (unsigned)(2 * s + 1), (unsigned)(8192 + 2 * s + 1)).a;
  } else {
    int m = 2 * s - 8192;
    r.a = tf2x32(key, (unsigned)m,       (unsigned)(m + 8192)).b;
    r.b = tf2x32(key, (unsigned)(m + 1), (unsigned)(m + 1 + 8192)).b;
  }
  return r;
#endif
}

// ------------------------- fp32 numerics (XLA-matched) ---------------------
__device__ __forceinline__ float acc_logf_(float x) {
  return (float)log((double)x);
}
__device__ __forceinline__ float acc_expf_(float x) {
  return (float)exp((double)x);
}

__device__ __forceinline__ float bits_to_uniform01_(unsigned bits) {
  return __uint_as_float((bits >> 9) | 0x3F800000u) - 1.0f;
}

__device__ __forceinline__ float xla_log1pf_(float t) {
  #pragma clang fp contract(off)
  float small_ = (1.0f + (-0.5f) * t) * t;
  float large_ = acc_logf_(t + 1.0f);
  return (fabsf(t) < 1e-4f) ? small_ : large_;
}

__device__ float xla_erfinv_(float x) {
  #pragma clang fp contract(off)
  float w = -xla_log1pf_(-(x * x));
  float p;
  if (w < 5.0f) {
    float ww = w - 2.5f;
    p = 2.81022636e-08f;
    p = 3.43273939e-07f + p * ww;
    p = -3.5233877e-06f + p * ww;
    p = -4.39150654e-06f + p * ww;
    p = 0.00021858087f + p * ww;
    p = -0.00125372503f + p * ww;
    p = -0.00417768164f + p * ww;
    p = 0.246640727f + p * ww;
    p = 1.50140941f + p * ww;
  } else {
    float ww = sqrtf(w) - 3.0f;
    p = -0.000200214257f;
    p = 0.000100950558f + p * ww;
    p = 0.00134934322f + p * ww;
    p = -0.00367342844f + p * ww;
    p = 0.00573950773f + p * ww;
    p = -0.0076224613f + p * ww;
    p = 0.00943887047f + p * ww;
    p = 1.00167406f + p * ww;
    p = 2.83297682f + p * ww;
  }
  return p * x;
}

__device__ float bits_to_normal_(unsigned bits) {
  #pragma clang fp contract(off)
  const float lo = __uint_as_float(0xBF7FFFFFu);
  float f = bits_to_uniform01_(bits);
  float u = f * 2.0f + lo;
  u = fmaxf(lo, u);
  return __uint_as_float(0x3FB504F3u) * xla_erfinv_(u);
}

__device__ __forceinline__ float softplus_(float x) {
  #pragma clang fp contract(off)
  float amax = fmaxf(x, 0.0f);
  float e = acc_expf_(-fabsf(x));
  return amax + xla_log1pf_(e);
}

__device__ __forceinline__ float sigmoid_(float v) { return 1.0f / (1.0f + expf(-v)); }

// bf16 round-to-nearest-even split helpers
__device__ __forceinline__ unsigned short f2bf_(float f) {
  unsigned u = __float_as_uint(f);
  unsigned r = (u + 0x7FFFu + ((u >> 16) & 1u)) >> 16;
  return (unsigned short)r;
}
__device__ __forceinline__ float bf2f_(unsigned short b) {
  return __uint_as_float(((unsigned)b) << 16);
}

// ------------------------- gamma / student-t sampler -----------------------
__device__ float gamma_sample_(KeyPair gkey, float alpha) {
  #pragma clang fp contract(off)
  const float third = 0.33333334f;
  float d = alpha - third;
  float c = third / sqrtf(d);
  KeyPair key, boost_sub;
  split2_(gkey, key, boost_sub);
  (void)boost_sub;
  float X = 0.0f, V = 1.0f, U = 2.0f;
  for (int guard = 0; guard < 1024; guard++) {
    float X2 = X * X;
    float sq = 1.0f - 0.0331f * (X2 * X2);
    bool cont = false;
    if (U >= sq) {
      float lhs = acc_logf_(U);
      float rhs = (X * 0.5f) + (d * ((1.0f - V) + acc_logf_(V)));
      cont = (lhs >= rhs);
    }
    if (!cont) break;
    KeyPair nkey, xkey, Ukey;
    split3_(key, nkey, xkey, Ukey);
    key = nkey;
    float x, v;
    KeyPair kk = xkey;
    do {
      KeyPair knew, sub;
      split2_(kk, knew, sub);
      kk = knew;
      x = bits_to_normal_(scalar_bits_(sub));
      v = 1.0f + x * c;
    } while (v <= 0.0f);
    X = x * x;
    V = (v * v) * v;
    U = bits_to_uniform01_(scalar_bits_(Ukey));
  }
  return d * V;
}

__device__ float sample_t_eps_(int k, int s, float df) {
  #pragma clang fp contract(off)
  KeyPair base; base.a = 0u; base.b = 42u;
  KeyPair tkey = tf2x32(base, 0u, (unsigned)k);
  KeyPair key_n, key_g;
  split2_(tkey, key_n, key_g);
  float n = bits_to_normal_(batch_bits_8192_(key_n, s));
  KeyPair gkey = subkey_of_8192_(key_g, s);
  float half_df = df * 0.5f;
  float g = gamma_sample_(gkey, half_df);
  return n * sqrtf(half_df / g);
}

// ------------------------------- kernels -----------------------------------

__global__ __launch_bounds__(256) void prep_kernel(
    const float* __restrict__ x, const float* __restrict__ x_mark,
    const float* __restrict__ y_mark, const float* __restrict__ W_emb,
    const float* __restrict__ b_emb, float* __restrict__ scale_p,
    float* __restrict__ tfe, float* __restrict__ emb_y) {
  int tid = threadIdx.x;
  if (tid == 0) {
    float s = 0.0f;
    for (int t = 0; t < HIST; t++) s += fabsf(x[t]);
    float m = s / 336.0f;
    scale_p[0] = fmaxf(m, 1e-5f);
  }
  for (int idx = tid; idx < HIST * EMB; idx += 256) {
    int t = idx / EMB, e = idx % EMB;
    float a = b_emb[e];
    for (int f = 0; f < 4; f++) a += x_mark[t * 4 + f] * W_emb[e * 4 + f];
    tfe[idx] = a;
  }
  for (int idx = tid; idx < PRED * EMB; idx += 256) {
    int kk = idx / EMB, e = idx % EMB;
    float a = b_emb[e];
    for (int f = 0; f < 4; f++) a += y_mark[kk * 4 + f] * W_emb[e * 4 + f];
    emb_y[idx] = a;
  }
}

__global__ __launch_bounds__(256) void enc_gi_kernel(
    const float* __restrict__ x, const float* __restrict__ tfe,
    const float* __restrict__ W_ih, const float* __restrict__ b_ih,
    const float* __restrict__ scale_p, float* __restrict__ enc_gi) {
  __shared__ float fe[EMB];
  __shared__ float xs_s;
  int t = blockIdx.x;
  int tid = threadIdx.x;
  if (tid < EMB) fe[tid] = tfe[t * EMB + tid];
  if (tid == 0) xs_s = x[t] / scale_p[0];
  __syncthreads();
  float xs = xs_s;
  for (int r = tid; r < 3 * HIDDEN; r += 256) {
    const float* wr = W_ih + (size_t)r * 41;
    float a = b_ih[r] + wr[0] * xs;
    #pragma unroll
    for (int e = 0; e < EMB; e++) a += wr[1 + e] * fe[e];
    enc_gi[(size_t)t * 1536 + r] = a;
  }
}

__global__ __launch_bounds__(256) void giy_kernel(
    const float* __restrict__ emb_y, const float* __restrict__ W_ih,
    const float* __restrict__ b_ih, float* __restrict__ giy) {
  __shared__ float fe[EMB];
  int k = blockIdx.x;
  int tid = threadIdx.x;
  if (tid < EMB) fe[tid] = emb_y[k * EMB + tid];
  __syncthreads();
  for (int r = tid; r < 3 * HIDDEN; r += 256) {
    const float* wr = W_ih + (size_t)r * 41;
    float a = b_ih[r];
    #pragma unroll
    for (int e = 0; e < EMB; e++) a += wr[1 + e] * fe[e];
    giy[(size_t)k * 1536 + r] = a;
  }
}

// W_hh -> 3 bf16 split planes, rearranged per jb-slab: Wr[sp][jb][g*64+jl][k]
__global__ __launch_bounds__(256) void wsplit_kernel(
    const float* __restrict__ W_hh, unsigned short* __restrict__ Wr) {
  int row = blockIdx.x;                 // 0..1535
  int g = row >> 9;
  int jg = row & 511;
  int jb = jg >> 6, jl = jg & 63;
  size_t dst = ((size_t)jb * 192 + g * 64 + jl) * 512;
  for (int k = threadIdx.x; k < 512; k += 256) {
    float w = W_hh[(size_t)row * 512 + k];
    unsigned short b0 = f2bf_(w);  float r1 = w - bf2f_(b0);
    unsigned short b1 = f2bf_(r1); float r2 = r1 - bf2f_(b1);
    unsigned short b2 = f2bf_(r2);
    Wr[dst + k] = b0;
    Wr[WPLANE + dst + k] = b1;
    Wr[2 * WPLANE + dst + k] = b2;
  }
}

// split h_T (512) into sT[3][512]
__global__ __launch_bounds__(256) void hsplit_kernel(
    const float* __restrict__ h_T, unsigned short* __restrict__ sT) {
  int i = threadIdx.x;
  for (int j = i; j < 512; j += 256) {
    float v = h_T[j];
    unsigned short b0 = f2bf_(v);  float r1 = v - bf2f_(b0);
    unsigned short b1 = f2bf_(r1); float r2 = r1 - bf2f_(b1);
    unsigned short b2 = f2bf_(r2);
    sT[j] = b0; sT[512 + j] = b1; sT[1024 + j] = b2;
  }
}

// broadcast sT rows into h3[3][8192][512]
__global__ __launch_bounds__(256) void h3bcast_kernel(
    const unsigned short* __restrict__ sT, unsigned short* __restrict__ h3) {
  int row = blockIdx.x;
  int tid = threadIdx.x;
  if (tid < 192) {
    int sp = tid >> 6, c = tid & 63;
    ((uint4*)(h3 + (size_t)sp * HPLANE + (size_t)row * 512))[c] =
        ((const uint4*)(sT + sp * 512))[c];
  }
}

// poll a tagged 64-bit gh word until its tag matches, return fp32 payload
__device__ __forceinline__ float pollv_(ull* p, unsigned want) {
  ull v = __hip_atomic_load(p, __ATOMIC_RELAXED, __HIP_MEMORY_SCOPE_AGENT);
  while ((unsigned)(v >> 32) != want) {
    __builtin_amdgcn_s_sleep(1);
    v = __hip_atomic_load(p, __ATOMIC_RELAXED, __HIP_MEMORY_SCOPE_AGENT);
  }
  return __uint_as_float((unsigned)v);
}

// persistent encoder GRU; tagged-word grid sync (1 cross-XCD round trip/step).
// Safety: slot written at iter t (tag t+1) is only overwritten at iter t+2
// (tag t+3); any block at iter t+2 consumed all tag-t+2 words, which were
// produced only after every block consumed all tag-t+1 words.
__global__ __launch_bounds__(256) void enc_gru_kernel(
    const float* __restrict__ enc_gi, const float* __restrict__ W_hh,
    const float* __restrict__ b_hh, ull* __restrict__ ghbuf,
    float* __restrict__ h_T) {
  __shared__ __align__(16) float hs[HIDDEN];
  int tid = threadIdx.x;
  int gtid = blockIdx.x * 256 + tid;
  int row = gtid >> 3;
  int sub = gtid & 7;

  float w[64];
  const float* wp = W_hh + (size_t)row * HIDDEN + sub * 64;
  #pragma unroll
  for (int i = 0; i < 16; i++) {
    float4 v = *(const float4*)(wp + 4 * i);
    w[4 * i + 0] = v.x; w[4 * i + 1] = v.y; w[4 * i + 2] = v.z; w[4 * i + 3] = v.w;
  }
  if (tid < 128) *(float4*)&hs[tid * 4] = make_float4(0.f, 0.f, 0.f, 0.f);
  float bhr0 = b_hh[tid],       bhz0 = b_hh[512 + tid],  bhn0 = b_hh[1024 + tid];
  float bhr1 = b_hh[256 + tid], bhz1 = b_hh[768 + tid],  bhn1 = b_hh[1280 + tid];
  __syncthreads();

  for (int t = 0; t < HIST; t++) {
    float p = 0.0f;
    const float4* hv = (const float4*)&hs[sub * 64];
    #pragma unroll
    for (int i = 0; i < 16; i++) {
      float4 v = hv[i];
      p += w[4 * i + 0] * v.x + w[4 * i + 1] * v.y +
           w[4 * i + 2] * v.z + w[4 * i + 3] * v.w;
    }
    p += __shfl_xor(p, 1, 64);
    p += __shfl_xor(p, 2, 64);
    p += __shfl_xor(p, 4, 64);
    unsigned want = (unsigned)(t + 1);
    ull* gb = ghbuf + (size_t)(t & 1) * 1536;
    if (sub == 0) {
      ull pk = ((ull)want << 32) | (ull)__float_as_uint(p);
      __hip_atomic_store(&gb[row], pk, __ATOMIC_RELAXED,
                         __HIP_MEMORY_SCOPE_AGENT);
    }
    // poll own 6 gh words (tag+value atomic together: no fences needed)
    float ghr0 = pollv_(&gb[tid], want);
    float ghz0 = pollv_(&gb[512 + tid], want);
    float ghn0 = pollv_(&gb[1024 + tid], want);
    float ghr1 = pollv_(&gb[256 + tid], want);
    float ghz1 = pollv_(&gb[768 + tid], want);
    float ghn1 = pollv_(&gb[1280 + tid], want);
    float hn0, hn1;
    {
      int j = tid;
      float gir = enc_gi[(size_t)t * 1536 + j];
      float giz = enc_gi[(size_t)t * 1536 + 512 + j];
      float gin = enc_gi[(size_t)t * 1536 + 1024 + j];
      float r = sigmoid_(gir + (ghr0 + bhr0));
      float z = sigmoid_(giz + (ghz0 + bhz0));
      float n = tanhf(gin + r * (ghn0 + bhn0));
      hn0 = (1.0f - z) * n + z * hs[j];
    }
    {
      int j = tid + 256;
      float gir = enc_gi[(size_t)t * 1536 + j];
      float giz = enc_gi[(size_t)t * 1536 + 512 + j];
      float gin = enc_gi[(size_t)t * 1536 + 1024 + j];
      float r = sigmoid_(gir + (ghr1 + bhr1));
      float z = sigmoid_(giz + (ghz1 + bhz1));
      float n = tanhf(gin + r * (ghn1 + bhn1));
      hn1 = (1.0f - z) * n + z * hs[j];
    }
    hs[tid] = hn0;
    hs[tid + 256] = hn1;
    __syncthreads();
  }
  if (blockIdx.x == 0 && tid < 128)
    *(float4*)&h_T[tid * 4] = *(float4*)&hs[tid * 4];
}

// ---------------------------------------------------------------------------
// Decoder GRU step via bf16 MFMA, 3-split x 6 products (unchanged round 3).
// ---------------------------------------------------------------------------
__global__ __launch_bounds__(256, 2) void dec_gru_mfma(
    const unsigned short* __restrict__ h3_in,   // [3][8192][512]
    const unsigned short* __restrict__ Wr,      // [3][8 jb][192][512]
    const float* __restrict__ giy_k, const float* __restrict__ b_hh,
    const float* __restrict__ W_ih, const float* __restrict__ tgt,
    int tgt_is_x, unsigned short* __restrict__ h3_out) {
  __shared__ unsigned short As[3][128][32];
  __shared__ unsigned short Bs[3][192][32];
  int b_ = blockIdx.x;
  int xcd = b_ & 7, slot = b_ >> 3;
  int g_ = xcd & 3, h_ = xcd >> 2;
  int mb = g_ * 16 + (slot & 15);     // 0..63
  int jb = h_ * 4 + (slot >> 4);      // 0..7
  int tid = threadIdx.x;
  int lane = tid & 63;
  int wave = tid >> 6;
  int wm = wave >> 1, wn = wave & 1;
  int s0 = mb * 128;
  int q = lane >> 4, c = lane & 15;

  f32x4 acc[4][6];
  #pragma unroll
  for (int i = 0; i < 4; i++)
    #pragma unroll
    for (int n = 0; n < 6; n++) acc[i][n] = (f32x4){0.f, 0.f, 0.f, 0.f};

  float hold[2][4][4];
  #pragma unroll
  for (int t = 0; t < 2; t++)
    #pragma unroll
    for (int i = 0; i < 4; i++)
      #pragma unroll
      for (int r = 0; r < 4; r++) hold[t][i][r] = 0.f;

  int kb_cap = jb * 64 + wn * 32;   // k-block holding this wave's j-columns

  for (int kb = 0; kb < HIDDEN; kb += 32) {
    #pragma unroll
    for (int r = 0; r < 6; r++) {
      int a = r * 256 + tid;
      int sp = a >> 9, rem = a & 511;
      int row = rem >> 2, c4 = rem & 3;
      uint4 v = *(const uint4*)(h3_in + (size_t)sp * HPLANE +
                                (size_t)(s0 + row) * 512 + kb + c4 * 8);
      *(uint4*)&As[sp][row][(c4 ^ (row & 3)) * 8] = v;
    }
    #pragma unroll
    for (int r = 0; r < 9; r++) {
      int b = r * 256 + tid;
      int sp = b / 768, rem = b % 768;
      int row = rem >> 2, c4 = rem & 3;
      uint4 v = *(const uint4*)(Wr + (size_t)sp * WPLANE +
                                ((size_t)jb * 192 + row) * 512 + kb + c4 * 8);
      *(uint4*)&Bs[sp][row][(c4 ^ (row & 3)) * 8] = v;
    }
    __syncthreads();

    if (kb == kb_cap) {
      #pragma unroll
      for (int t = 0; t < 2; t++)
        #pragma unroll
        for (int i = 0; i < 4; i++)
          #pragma unroll
          for (int reg = 0; reg < 4; reg++) {
            int m = wm * 64 + i * 16 + q * 4 + reg;
            int cc = t * 16 + c;
            int idx = (((cc >> 3) ^ (m & 3)) << 3) + (cc & 7);
            hold[t][i][reg] = bf2f_(As[0][m][idx]) + bf2f_(As[1][m][idx]) +
                              bf2f_(As[2][m][idx]);
          }
    }

    short8 af[4][3];
    #pragma unroll
    for (int i = 0; i < 4; i++) {
      int m = wm * 64 + i * 16 + c;
      #pragma unroll
      for (int sp = 0; sp < 3; sp++)
        af[i][sp] = *(const short8*)&As[sp][m][(q ^ (c & 3)) * 8];
    }
    #pragma unroll
    for (int nt = 0; nt < 6; nt++) {
      int g = nt >> 1, t = nt & 1;
      int rB = g * 64 + wn * 32 + t * 16 + c;
      short8 bh = *(const short8*)&Bs[0][rB][(q ^ (c & 3)) * 8];
      short8 bm = *(const short8*)&Bs[1][rB][(q ^ (c & 3)) * 8];
      short8 bl = *(const short8*)&Bs[2][rB][(q ^ (c & 3)) * 8];
      #pragma unroll
      for (int i = 0; i < 4; i++) {
        acc[i][nt] = __builtin_amdgcn_mfma_f32_16x16x32_bf16(af[i][0], bh, acc[i][nt], 0, 0, 0);
        acc[i][nt] = __builtin_amdgcn_mfma_f32_16x16x32_bf16(af[i][0], bm, acc[i][nt], 0, 0, 0);
        acc[i][nt] = __builtin_amdgcn_mfma_f32_16x16x32_bf16(af[i][1], bh, acc[i][nt], 0, 0, 0);
        acc[i][nt] = __builtin_amdgcn_mfma_f32_16x16x32_bf16(af[i][0], bl, acc[i][nt], 0, 0, 0);
        acc[i][nt] = __builtin_amdgcn_mfma_f32_16x16x32_bf16(af[i][2], bh, acc[i][nt], 0, 0, 0);
        acc[i][nt] = __builtin_amdgcn_mfma_f32_16x16x32_bf16(af[i][1], bm, acc[i][nt], 0, 0, 0);
      }
    }
    __syncthreads();
  }

  #pragma unroll
  for (int t = 0; t < 2; t++) {
    int j = jb * 64 + wn * 32 + t * 16 + c;
    float gyr = giy_k[j], gyz = giy_k[512 + j], gyn = giy_k[1024 + j];
    float w0r = W_ih[(size_t)j * 41];
    float w0z = W_ih[(size_t)(512 + j) * 41];
    float w0n = W_ih[(size_t)(1024 + j) * 41];
    float bhr = b_hh[j], bhz = b_hh[512 + j], bhn = b_hh[1024 + j];
    #pragma unroll
    for (int i = 0; i < 4; i++) {
      #pragma unroll
      for (int reg = 0; reg < 4; reg++) {
        int s = s0 + wm * 64 + i * 16 + q * 4 + reg;
        float tg = tgt_is_x ? tgt[HIST - 1] : tgt[s];
        size_t off = (size_t)s * 512 + j;
        float h_old = hold[t][i][reg];
        float gr = (gyr + w0r * tg) + (acc[i][t][reg] + bhr);
        float gz = (gyz + w0z * tg) + (acc[i][2 + t][reg] + bhz);
        float gn_i = gyn + w0n * tg;
        float gn_h = acc[i][4 + t][reg] + bhn;
        float r_ = sigmoid_(gr);
        float z_ = sigmoid_(gz);
        float n_ = tanhf(gn_i + r_ * gn_h);
        float hn = (1.0f - z_) * n_ + z_ * h_old;
        unsigned short b0 = f2bf_(hn);  float r1 = hn - bf2f_(b0);
        unsigned short b1 = f2bf_(r1);  float r2 = r1 - bf2f_(b1);
        unsigned short b2 = f2bf_(r2);
        h3_out[off] = b0;
        h3_out[HPLANE + off] = b1;
        h3_out[2 * HPLANE + off] = b2;
      }
    }
  }
}

// heads + student-t sampling. 64-thread blocks (128 blocks): 4x CU coverage
// for the 24 MB h3 read. Accumulation order identical to previous rounds.
__global__ __launch_bounds__(64) void dec_head_kernel(
    const unsigned short* __restrict__ h3, const float* __restrict__ W_df,
    const float* __restrict__ b_df, const float* __restrict__ W_loc,
    const float* __restrict__ b_loc, const float* __restrict__ W_sc,
    const float* __restrict__ b_sc, const float* __restrict__ scale_p,
    float* __restrict__ tgt, float* __restrict__ out, int k) {
  #pragma clang fp contract(off)
  int s = blockIdx.x * 64 + threadIdx.x;
  size_t base = (size_t)s * 512;
  float adf = 0.f, alo = 0.f, asc = 0.f;
  for (int i = 0; i < 64; i++) {
    uint4 q0 = *(const uint4*)(h3 + base + 8 * i);
    uint4 q1 = *(const uint4*)(h3 + HPLANE + base + 8 * i);
    uint4 q2 = *(const uint4*)(h3 + 2 * HPLANE + base + 8 * i);
    float x0 = bf2f_((unsigned short)(q0.x & 0xffffu)) + bf2f_((unsigned short)(q1.x & 0xffffu)) + bf2f_((unsigned short)(q2.x & 0xffffu));
    float x1 = bf2f_((unsigned short)(q0.x >> 16))     + bf2f_((unsigned short)(q1.x >> 16))     + bf2f_((unsigned short)(q2.x >> 16));
    float x2 = bf2f_((unsigned short)(q0.y & 0xffffu)) + bf2f_((unsigned short)(q1.y & 0xffffu)) + bf2f_((unsigned short)(q2.y & 0xffffu));
    float x3 = bf2f_((unsigned short)(q0.y >> 16))     + bf2f_((unsigned short)(q1.y >> 16))     + bf2f_((unsigned short)(q2.y >> 16));
    float x4 = bf2f_((unsigned short)(q0.z & 0xffffu)) + bf2f_((unsigned short)(q1.z & 0xffffu)) + bf2f_((unsigned short)(q2.z & 0xffffu));
    float x5 = bf2f_((unsigned short)(q0.z >> 16))     + bf2f_((unsigned short)(q1.z >> 16))     + bf2f_((unsigned short)(q2.z >> 16));
    float x6 = bf2f_((unsigned short)(q0.w & 0xffffu)) + bf2f_((unsigned short)(q1.w & 0xffffu)) + bf2f_((unsigned short)(q2.w & 0xffffu));
    float x7 = bf2f_((unsigned short)(q0.w >> 16))     + bf2f_((unsigned short)(q1.w >> 16))     + bf2f_((unsigned short)(q2.w >> 16));
    float4 wd0 = ((const float4*)W_df)[2 * i],  wd1 = ((const float4*)W_df)[2 * i + 1];
    float4 wl0 = ((const float4*)W_loc)[2 * i], wl1 = ((const float4*)W_loc)[2 * i + 1];
    float4 ws0 = ((const float4*)W_sc)[2 * i],  ws1 = ((const float4*)W_sc)[2 * i + 1];
    adf += x0 * wd0.x; adf += x1 * wd0.y; adf += x2 * wd0.z; adf += x3 * wd0.w;
    adf += x4 * wd1.x; adf += x5 * wd1.y; adf += x6 * wd1.z; adf += x7 * wd1.w;
    alo += x0 * wl0.x; alo += x1 * wl0.y; alo += x2 * wl0.z; alo += x3 * wl0.w;
    alo += x4 * wl1.x; alo += x5 * wl1.y; alo += x6 * wl1.z; alo += x7 * wl1.w;
    asc += x0 * ws0.x; asc += x1 * ws0.y; asc += x2 * ws0.z; asc += x3 * ws0.w;
    asc += x4 * ws1.x; asc += x5 * ws1.y; asc += x6 * ws1.z; asc += x7 * ws1.w;
  }
  float df = 2.0f + softplus_(adf + b_df[0]);
  float loc = alo + b_loc[0];
  float sc = softplus_(asc + b_sc[0]);
  float eps = sample_t_eps_(k, s, df);
  float smp = (loc + sc * eps) * scale_p[0];
  out[(size_t)s * PRED + k] = smp;
  tgt[s] = smp;
}

// ------------------------------- launcher ----------------------------------
extern "C" void kernel_launch(void* const* d_in, const int* in_sizes, int n_in,
                              void* d_out, int out_size, void* d_ws, size_t ws_size,
                              hipStream_t stream) {
  const float* x      = (const float*)d_in[0];
  const float* x_mark = (const float*)d_in[1];
  const float* y_mark = (const float*)d_in[2];
  const float* W_emb  = (const float*)d_in[4];
  const float* b_emb  = (const float*)d_in[5];
  const float* W_ih   = (const float*)d_in[6];
  const float* W_hh   = (const float*)d_in[7];
  const float* b_ih   = (const float*)d_in[8];
  const float* b_hh   = (const float*)d_in[9];
  const float* W_df   = (const float*)d_in[10];
  const float* b_df   = (const float*)d_in[11];
  const float* W_loc  = (const float*)d_in[12];
  const float* b_loc  = (const float*)d_in[13];
  const float* W_sc   = (const float*)d_in[14];
  const float* b_sc   = (const float*)d_in[15];
  float* out = (float*)d_out;

  float* w = (float*)d_ws;
  unsigned short* h3_a = (unsigned short*)(w);                 // 3*8192*512 sh
  unsigned short* h3_b = (unsigned short*)(w + 6291456);       // 3*8192*512 sh
  unsigned short* Wr   = (unsigned short*)(w + 12582912);      // 3*1536*512 sh
  float* enc_gi = w + 13762560;             // 336*1536
  float* giy    = w + 14278656;             // 48*1536
  float* tfe    = w + 14352384;             // 336*40
  float* emb_y  = w + 14365824;             // 48*40
  ull* ghbuf    = (ull*)(w + 14367744);     // 2*1536 ull (8B aligned)
  float* h_T    = w + 14373888;             // 512
  unsigned short* sT = (unsigned short*)(w + 14374400);  // 3*512 sh
  float* tgt    = w + 14375168;             // 8192
  float* scale_p = w + 14383360;            // 1

  prep_kernel<<<1, 256, 0, stream>>>(x, x_mark, y_mark, W_emb, b_emb,
                                     scale_p, tfe, emb_y);
  enc_gi_kernel<<<HIST, 256, 0, stream>>>(x, tfe, W_ih, b_ih, scale_p, enc_gi);
  giy_kernel<<<PRED, 256, 0, stream>>>(emb_y, W_ih, b_ih, giy);
  wsplit_kernel<<<1536, 256, 0, stream>>>(W_hh, Wr);
  enc_gru_kernel<<<ENC_BLOCKS, 256, 0, stream>>>(enc_gi, W_hh, b_hh, ghbuf,
                                                 h_T);
  hsplit_kernel<<<1, 256, 0, stream>>>(h_T, sT);
  h3bcast_kernel<<<S_N, 256, 0, stream>>>(sT, h3_a);

  for (int k = 0; k < PRED; k++) {
    const unsigned short* h_in = (k % 2 == 0) ? h3_a : h3_b;
    unsigned short* h_o = (k % 2 == 0) ? h3_b : h3_a;
    dec_gru_mfma<<<512, 256, 0, stream>>>(
        h_in, Wr, giy + (size_t)k * 1536, b_hh, W_ih,
        (k == 0) ? x : tgt, (k == 0) ? 1 : 0, h_o);
    dec_head_kernel<<<S_N / 64, 64, 0, stream>>>(
        h_o, W_df, b_df, W_loc, b_loc, W_sc, b_sc, scale_p, tgt, out, k);
  }
}

// Round 5
// 6528.340 us; speedup vs baseline: 1.6897x; 1.0497x over previous
//
#include <hip/hip_runtime.h>
#include <cmath>

// ---------------------------------------------------------------------------
// DeepAR sampling on MI355X. Round 5:
//  - decoder GEMM: bf16 3-split/6-product -> fp16 2-split/3-product.
//    h in (-1,1) (tanh-gated) and |W|~0.05 fit fp16; residuals scaled 2^12.
//    Dropped f1*g1 ~ 2^-24 rel => same ~1e-7 gh quality, half the MFMA work,
//    2/3 the staging bytes. Tile 128x96, grid 64x16=1024, XCD-swizzled.
//  - encoder reverted to round-3 flag-array barrier (round-4 tagged words
//    REGRESSED: 6 serialized cross-XCD spin loops vs 1 flag + parallel loads).
//  - dec_head reads 2 fp16 planes (16 MB vs 24 MB).
// ---------------------------------------------------------------------------

#define JAX_PARTITIONABLE 1

#define HIDDEN 512
#define EMB 40
#define HIST 336
#define PRED 48
#define S_N 8192
#define ENC_BLOCKS 48

#define HPLANE (8192 * 512)     // shorts per h split plane
#define WPLANE (1536 * 512)     // shorts per W split plane
#define INV4096 (1.0f / 4096.0f)

typedef __attribute__((ext_vector_type(8))) _Float16 half8;
typedef __attribute__((ext_vector_type(4))) float f32x4;

// ------------------------------- threefry ----------------------------------
struct KeyPair { unsigned a, b; };

__device__ __forceinline__ unsigned rotl32_(unsigned v, unsigned s) {
  return (v << s) | (v >> (32u - s));
}

__device__ __forceinline__ KeyPair tf2x32(KeyPair k, unsigned x0, unsigned x1) {
  unsigned ks0 = k.a, ks1 = k.b, ks2 = ks0 ^ ks1 ^ 0x1BD11BDAu;
  x0 += ks0; x1 += ks1;
#define TF_R(r) { x0 += x1; x1 = rotl32_(x1, r); x1 ^= x0; }
  TF_R(13u) TF_R(15u) TF_R(26u) TF_R(6u)  x0 += ks1; x1 += ks2 + 1u;
  TF_R(17u) TF_R(29u) TF_R(16u) TF_R(24u) x0 += ks2; x1 += ks0 + 2u;
  TF_R(13u) TF_R(15u) TF_R(26u) TF_R(6u)  x0 += ks0; x1 += ks1 + 3u;
  TF_R(17u) TF_R(29u) TF_R(16u) TF_R(24u) x0 += ks1; x1 += ks2 + 4u;
  TF_R(13u) TF_R(15u) TF_R(26u) TF_R(6u)  x0 += ks2; x1 += ks0 + 5u;
#undef TF_R
  KeyPair r; r.a = x0; r.b = x1; return r;
}

__device__ __forceinline__ void split2_(KeyPair key, KeyPair& r0, KeyPair& r1) {
#if JAX_PARTITIONABLE
  r0 = tf2x32(key, 0u, 0u);
  r1 = tf2x32(key, 0u, 1u);
#else
  KeyPair p0 = tf2x32(key, 0u, 2u);
  KeyPair p1 = tf2x32(key, 1u, 3u);
  r0.a = p0.a; r0.b = p1.a;
  r1.a = p0.b; r1.b = p1.b;
#endif
}

__device__ __forceinline__ void split3_(KeyPair key, KeyPair& r0, KeyPair& r1, KeyPair& r2) {
#if JAX_PARTITIONABLE
  r0 = tf2x32(key, 0u, 0u);
  r1 = tf2x32(key, 0u, 1u);
  r2 = tf2x32(key, 0u, 2u);
#else
  KeyPair p0 = tf2x32(key, 0u, 3u);
  KeyPair p1 = tf2x32(key, 1u, 4u);
  KeyPair p2 = tf2x32(key, 2u, 5u);
  r0.a = p0.a; r0.b = p1.a;
  r1.a = p2.a; r1.b = p0.b;
  r2.a = p1.b; r2.b = p2.b;
#endif
}

__device__ __forceinline__ unsigned scalar_bits_(KeyPair key) {
#if JAX_PARTITIONABLE
  KeyPair p = tf2x32(key, 0u, 0u);
  return p.a ^ p.b;
#else
  return tf2x32(key, 0u, 0u).a;
#endif
}

__device__ __forceinline__ unsigned batch_bits_8192_(KeyPair key, int s) {
#if JAX_PARTITIONABLE
  KeyPair p = tf2x32(key, 0u, (unsigned)s);
  return p.a ^ p.b;
#else
  if (s < 4096) return tf2x32(key, (unsigned)s, (unsigned)(4096 + s)).a;
  return tf2x32(key, (unsigned)(s - 4096), (unsigned)s).b;
#endif
}

__device__ __forceinline__ KeyPair subkey_of_8192_(KeyPair key, int s) {
#if JAX_PARTITIONABLE
  return tf2x32(key, 0u, (unsigned)s);
#else
  KeyPair r;
  if (s < 4096) {
    r.a = tf2x32(key, (unsigned)(2 * s),     (unsigned)(8192 + 2 * s)).a;
    r.b = tf2x32(key, (unsigned)(2 * s + 1), (unsigned)(8192 + 2 * s + 1)).a;
  } else {
    int m = 2 * s - 8192;
    r.a = tf2x32(key, (unsigned)m,       (unsigned)(m + 8192)).b;
    r.b = tf2x32(key, (unsigned)(m + 1), (unsigned)(m + 1 + 8192)).b;
  }
  return r;
#endif
}

// ------------------------- fp32 numerics (XLA-matched) ---------------------
__device__ __forceinline__ float acc_logf_(float x) {
  return (float)log((double)x);
}
__device__ __forceinline__ float acc_expf_(float x) {
  return (float)exp((double)x);
}

__device__ __forceinline__ float bits_to_uniform01_(unsigned bits) {
  return __uint_as_float((bits >> 9) | 0x3F800000u) - 1.0f;
}

__device__ __forceinline__ float xla_log1pf_(float t) {
  #pragma clang fp contract(off)
  float small_ = (1.0f + (-0.5f) * t) * t;
  float large_ = acc_logf_(t + 1.0f);
  return (fabsf(t) < 1e-4f) ? small_ : large_;
}

__device__ float xla_erfinv_(float x) {
  #pragma clang fp contract(off)
  float w = -xla_log1pf_(-(x * x));
  float p;
  if (w < 5.0f) {
    float ww = w - 2.5f;
    p = 2.81022636e-08f;
    p = 3.43273939e-07f + p * ww;
    p = -3.5233877e-06f + p * ww;
    p = -4.39150654e-06f + p * ww;
    p = 0.00021858087f + p * ww;
    p = -0.00125372503f + p * ww;
    p = -0.00417768164f + p * ww;
    p = 0.246640727f + p * ww;
    p = 1.50140941f + p * ww;
  } else {
    float ww = sqrtf(w) - 3.0f;
    p = -0.000200214257f;
    p = 0.000100950558f + p * ww;
    p = 0.00134934322f + p * ww;
    p = -0.00367342844f + p * ww;
    p = 0.00573950773f + p * ww;
    p = -0.0076224613f + p * ww;
    p = 0.00943887047f + p * ww;
    p = 1.00167406f + p * ww;
    p = 2.83297682f + p * ww;
  }
  return p * x;
}

__device__ float bits_to_normal_(unsigned bits) {
  #pragma clang fp contract(off)
  const float lo = __uint_as_float(0xBF7FFFFFu);
  float f = bits_to_uniform01_(bits);
  float u = f * 2.0f + lo;
  u = fmaxf(lo, u);
  return __uint_as_float(0x3FB504F3u) * xla_erfinv_(u);
}

__device__ __forceinline__ float softplus_(float x) {
  #pragma clang fp contract(off)
  float amax = fmaxf(x, 0.0f);
  float e = acc_expf_(-fabsf(x));
  return amax + xla_log1pf_(e);
}

__device__ __forceinline__ float sigmoid_(float v) { return 1.0f / (1.0f + expf(-v)); }

// fp16 split helpers (round-to-nearest-even via cast)
__device__ __forceinline__ unsigned short f2h_(float f) {
  _Float16 h = (_Float16)f;
  return __builtin_bit_cast(unsigned short, h);
}
__device__ __forceinline__ float h2f_(unsigned short b) {
  return (float)__builtin_bit_cast(_Float16, b);
}

// ------------------------- gamma / student-t sampler -----------------------
__device__ float gamma_sample_(KeyPair gkey, float alpha) {
  #pragma clang fp contract(off)
  const float third = 0.33333334f;
  float d = alpha - third;
  float c = third / sqrtf(d);
  KeyPair key, boost_sub;
  split2_(gkey, key, boost_sub);
  (void)boost_sub;
  float X = 0.0f, V = 1.0f, U = 2.0f;
  for (int guard = 0; guard < 1024; guard++) {
    float X2 = X * X;
    float sq = 1.0f - 0.0331f * (X2 * X2);
    bool cont = false;
    if (U >= sq) {
      float lhs = acc_logf_(U);
      float rhs = (X * 0.5f) + (d * ((1.0f - V) + acc_logf_(V)));
      cont = (lhs >= rhs);
    }
    if (!cont) break;
    KeyPair nkey, xkey, Ukey;
    split3_(key, nkey, xkey, Ukey);
    key = nkey;
    float x, v;
    KeyPair kk = xkey;
    do {
      KeyPair knew, sub;
      split2_(kk, knew, sub);
      kk = knew;
      x = bits_to_normal_(scalar_bits_(sub));
      v = 1.0f + x * c;
    } while (v <= 0.0f);
    X = x * x;
    V = (v * v) * v;
    U = bits_to_uniform01_(scalar_bits_(Ukey));
  }
  return d * V;
}

__device__ float sample_t_eps_(int k, int s, float df) {
  #pragma clang fp contract(off)
  KeyPair base; base.a = 0u; base.b = 42u;
  KeyPair tkey = tf2x32(base, 0u, (unsigned)k);
  KeyPair key_n, key_g;
  split2_(tkey, key_n, key_g);
  float n = bits_to_normal_(batch_bits_8192_(key_n, s));
  KeyPair gkey = subkey_of_8192_(key_g, s);
  float half_df = df * 0.5f;
  float g = gamma_sample_(gkey, half_df);
  return n * sqrtf(half_df / g);
}

// ------------------------------- kernels -----------------------------------

__global__ __launch_bounds__(256) void prep_kernel(
    const float* __restrict__ x, const float* __restrict__ x_mark,
    const float* __restrict__ y_mark, const float* __restrict__ W_emb,
    const float* __restrict__ b_emb, float* __restrict__ scale_p,
    float* __restrict__ tfe, float* __restrict__ emb_y,
    unsigned* __restrict__ flags) {
  int tid = threadIdx.x;
  if (tid == 0) {
    float s = 0.0f;
    for (int t = 0; t < HIST; t++) s += fabsf(x[t]);
    float m = s / 336.0f;
    scale_p[0] = fmaxf(m, 1e-5f);
  }
  for (int i = tid; i < ENC_BLOCKS * 16; i += 256) flags[i] = 0u;
  for (int idx = tid; idx < HIST * EMB; idx += 256) {
    int t = idx / EMB, e = idx % EMB;
    float a = b_emb[e];
    for (int f = 0; f < 4; f++) a += x_mark[t * 4 + f] * W_emb[e * 4 + f];
    tfe[idx] = a;
  }
  for (int idx = tid; idx < PRED * EMB; idx += 256) {
    int kk = idx / EMB, e = idx % EMB;
    float a = b_emb[e];
    for (int f = 0; f < 4; f++) a += y_mark[kk * 4 + f] * W_emb[e * 4 + f];
    emb_y[idx] = a;
  }
}

__global__ __launch_bounds__(256) void enc_gi_kernel(
    const float* __restrict__ x, const float* __restrict__ tfe,
    const float* __restrict__ W_ih, const float* __restrict__ b_ih,
    const float* __restrict__ scale_p, float* __restrict__ enc_gi) {
  __shared__ float fe[EMB];
  __shared__ float xs_s;
  int t = blockIdx.x;
  int tid = threadIdx.x;
  if (tid < EMB) fe[tid] = tfe[t * EMB + tid];
  if (tid == 0) xs_s = x[t] / scale_p[0];
  __syncthreads();
  float xs = xs_s;
  for (int r = tid; r < 3 * HIDDEN; r += 256) {
    const float* wr = W_ih + (size_t)r * 41;
    float a = b_ih[r] + wr[0] * xs;
    #pragma unroll
    for (int e = 0; e < EMB; e++) a += wr[1 + e] * fe[e];
    enc_gi[(size_t)t * 1536 + r] = a;
  }
}

__global__ __launch_bounds__(256) void giy_kernel(
    const float* __restrict__ emb_y, const float* __restrict__ W_ih,
    const float* __restrict__ b_ih, float* __restrict__ giy) {
  __shared__ float fe[EMB];
  int k = blockIdx.x;
  int tid = threadIdx.x;
  if (tid < EMB) fe[tid] = emb_y[k * EMB + tid];
  __syncthreads();
  for (int r = tid; r < 3 * HIDDEN; r += 256) {
    const float* wr = W_ih + (size_t)r * 41;
    float a = b_ih[r];
    #pragma unroll
    for (int e = 0; e < EMB; e++) a += wr[1 + e] * fe[e];
    giy[(size_t)k * 1536 + r] = a;
  }
}

// W_hh -> 2 fp16 split planes, rearranged per 32-col jb-slab:
// Wr[sp][jb*96 + g*32 + jl][k],  row = g*512 + jb*32 + jl
__global__ __launch_bounds__(256) void wsplit_kernel(
    const float* __restrict__ W_hh, unsigned short* __restrict__ Wr) {
  int row = blockIdx.x;                 // 0..1535
  int g = row >> 9;
  int jg = row & 511;
  int jb = jg >> 5, jl = jg & 31;
  size_t dst = ((size_t)jb * 96 + g * 32 + jl) * 512;
  for (int k = threadIdx.x; k < 512; k += 256) {
    float w = W_hh[(size_t)row * 512 + k];
    unsigned short g0 = f2h_(w);
    float r1 = (w - h2f_(g0)) * 4096.0f;
    unsigned short g1 = f2h_(r1);
    Wr[dst + k] = g0;
    Wr[WPLANE + dst + k] = g1;
  }
}

// split h_T (512) into sT[2][512] fp16 planes
__global__ __launch_bounds__(256) void hsplit_kernel(
    const float* __restrict__ h_T, unsigned short* __restrict__ sT) {
  int i = threadIdx.x;
  for (int j = i; j < 512; j += 256) {
    float v = h_T[j];
    unsigned short f0 = f2h_(v);
    float r1 = (v - h2f_(f0)) * 4096.0f;
    sT[j] = f0;
    sT[512 + j] = f2h_(r1);
  }
}

// broadcast sT rows into h2[2][8192][512]
__global__ __launch_bounds__(128) void h2bcast_kernel(
    const unsigned short* __restrict__ sT, unsigned short* __restrict__ h2) {
  int row = blockIdx.x;
  int tid = threadIdx.x;
  int sp = tid >> 6, c = tid & 63;
  ((uint4*)(h2 + (size_t)sp * HPLANE + (size_t)row * 512))[c] =
      ((const uint4*)(sT + sp * 512))[c];
}

// persistent encoder GRU; round-3 flag-array grid barrier
__global__ __launch_bounds__(256) void enc_gru_kernel(
    const float* __restrict__ enc_gi, const float* __restrict__ W_hh,
    const float* __restrict__ b_hh, float* __restrict__ ghbuf,
    unsigned* __restrict__ flags, float* __restrict__ h_T) {
  __shared__ __align__(16) float hs[HIDDEN];
  int tid = threadIdx.x;
  int gtid = blockIdx.x * 256 + tid;
  int row = gtid >> 3;
  int sub = gtid & 7;

  float w[64];
  const float* wp = W_hh + (size_t)row * HIDDEN + sub * 64;
  #pragma unroll
  for (int i = 0; i < 16; i++) {
    float4 v = *(const float4*)(wp + 4 * i);
    w[4 * i + 0] = v.x; w[4 * i + 1] = v.y; w[4 * i + 2] = v.z; w[4 * i + 3] = v.w;
  }
  if (tid < 128) *(float4*)&hs[tid * 4] = make_float4(0.f, 0.f, 0.f, 0.f);
  float bhr0 = b_hh[tid],       bhz0 = b_hh[512 + tid],  bhn0 = b_hh[1024 + tid];
  float bhr1 = b_hh[256 + tid], bhz1 = b_hh[768 + tid],  bhn1 = b_hh[1280 + tid];
  __syncthreads();

  for (int t = 0; t < HIST; t++) {
    float p = 0.0f;
    const float4* hv = (const float4*)&hs[sub * 64];
    #pragma unroll
    for (int i = 0; i < 16; i++) {
      float4 v = hv[i];
      p += w[4 * i + 0] * v.x + w[4 * i + 1] * v.y +
           w[4 * i + 2] * v.z + w[4 * i + 3] * v.w;
    }
    p += __shfl_xor(p, 1, 64);
    p += __shfl_xor(p, 2, 64);
    p += __shfl_xor(p, 4, 64);
    int par = t & 1;
    if (sub == 0)
      __hip_atomic_store(&ghbuf[par * 1536 + row], p, __ATOMIC_RELAXED,
                         __HIP_MEMORY_SCOPE_AGENT);
    __syncthreads();
    if (tid == 0)
      __hip_atomic_store(&flags[blockIdx.x * 16], (unsigned)(t + 1),
                         __ATOMIC_RELEASE, __HIP_MEMORY_SCOPE_AGENT);
    if (tid < ENC_BLOCKS) {
      while (__hip_atomic_load(&flags[tid * 16], __ATOMIC_ACQUIRE,
                               __HIP_MEMORY_SCOPE_AGENT) < (unsigned)(t + 1))
        __builtin_amdgcn_s_sleep(1);
    }
    __syncthreads();
    float hn0, hn1;
    {
      int j = tid;
      float ghr = __hip_atomic_load(&ghbuf[par * 1536 + j], __ATOMIC_RELAXED, __HIP_MEMORY_SCOPE_AGENT);
      float ghz = __hip_atomic_load(&ghbuf[par * 1536 + 512 + j], __ATOMIC_RELAXED, __HIP_MEMORY_SCOPE_AGENT);
      float ghn = __hip_atomic_load(&ghbuf[par * 1536 + 1024 + j], __ATOMIC_RELAXED, __HIP_MEMORY_SCOPE_AGENT);
      float gir = enc_gi[(size_t)t * 1536 + j];
      float giz = enc_gi[(size_t)t * 1536 + 512 + j];
      float gin = enc_gi[(size_t)t * 1536 + 1024 + j];
      float r = sigmoid_(gir + (ghr + bhr0));
      float z = sigmoid_(giz + (ghz + bhz0));
      float n = tanhf(gin + r * (ghn + bhn0));
      hn0 = (1.0f - z) * n + z * hs[j];
    }
    {
      int j = tid + 256;
      float ghr = __hip_atomic_load(&ghbuf[par * 1536 + j], __ATOMIC_RELAXED, __HIP_MEMORY_SCOPE_AGENT);
      float ghz = __hip_atomic_load(&ghbuf[par * 1536 + 512 + j], __ATOMIC_RELAXED, __HIP_MEMORY_SCOPE_AGENT);
      float ghn = __hip_atomic_load(&ghbuf[par * 1536 + 1024 + j], __ATOMIC_RELAXED, __HIP_MEMORY_SCOPE_AGENT);
      float gir = enc_gi[(size_t)t * 1536 + j];
      float giz = enc_gi[(size_t)t * 1536 + 512 + j];
      float gin = enc_gi[(size_t)t * 1536 + 1024 + j];
      float r = sigmoid_(gir + (ghr + bhr1));
      float z = sigmoid_(giz + (ghz + bhz1));
      float n = tanhf(gin + r * (ghn + bhn1));
      hn1 = (1.0f - z) * n + z * hs[j];
    }
    hs[tid] = hn0;
    hs[tid + 256] = hn1;
    __syncthreads();
  }
  if (blockIdx.x == 0 && tid < 128)
    *(float4*)&h_T[tid * 4] = *(float4*)&hs[tid * 4];
}

// ---------------------------------------------------------------------------
// Decoder GRU step via fp16 MFMA, 2-split x 3 products.
// Block tile: 128 samples x 32 hidden cols x 3 gates (96 N-rows).
// Grid 1024, XCD-swizzled (8 mb x 16 jb per XCD). 4 waves (2x2).
// gh = acc_main + acc_corr * 2^-12.
// ---------------------------------------------------------------------------
__global__ __launch_bounds__(256, 2) void dec_gru_mfma(
    const unsigned short* __restrict__ h2_in,   // [2][8192][512] fp16
    const unsigned short* __restrict__ Wr,      // [2][16 jb][96][512] fp16
    const float* __restrict__ giy_k, const float* __restrict__ b_hh,
    const float* __restrict__ W_ih, const float* __restrict__ tgt,
    int tgt_is_x, unsigned short* __restrict__ h2_out) {
  __shared__ unsigned short As[2][128][32];
  __shared__ unsigned short Bs[2][96][32];
  int b_ = blockIdx.x;
  int xcd = b_ & 7, slot = b_ >> 3;          // slot 0..127
  int mb = xcd * 8 + (slot & 7);             // 0..63
  int jb = slot >> 3;                        // 0..15
  int tid = threadIdx.x;
  int lane = tid & 63;
  int wave = tid >> 6;
  int wm = wave >> 1, wn = wave & 1;
  int s0 = mb * 128;
  int q = lane >> 4, c = lane & 15;

  f32x4 accm[4][3], accc[4][3];
  #pragma unroll
  for (int i = 0; i < 4; i++)
    #pragma unroll
    for (int g = 0; g < 3; g++) {
      accm[i][g] = (f32x4){0.f, 0.f, 0.f, 0.f};
      accc[i][g] = (f32x4){0.f, 0.f, 0.f, 0.f};
    }

  float hold[4][4];
  #pragma unroll
  for (int i = 0; i < 4; i++)
    #pragma unroll
    for (int r = 0; r < 4; r++) hold[i][r] = 0.f;

  int kb_cap = jb * 32;   // k-block holding this block's j-columns

  for (int kb = 0; kb < HIDDEN; kb += 32) {
    // stage A: 2 planes x 128 rows x 32k (1024 16B-chunks, 4/thread)
    #pragma unroll
    for (int r = 0; r < 4; r++) {
      int a = r * 256 + tid;
      int sp = a >> 9, rem = a & 511;
      int row = rem >> 2, c4 = rem & 3;
      uint4 v = *(const uint4*)(h2_in + (size_t)sp * HPLANE +
                                (size_t)(s0 + row) * 512 + kb + c4 * 8);
      *(uint4*)&As[sp][row][(c4 ^ (row & 3)) * 8] = v;
    }
    // stage B: 2 planes x 96 rows x 32k (768 chunks, 3/thread)
    #pragma unroll
    for (int r = 0; r < 3; r++) {
      int b = r * 256 + tid;
      int sp = (b >= 384) ? 1 : 0;
      int rem = b - sp * 384;
      int row = rem >> 2, c4 = rem & 3;
      uint4 v = *(const uint4*)(Wr + (size_t)sp * WPLANE +
                                ((size_t)jb * 96 + row) * 512 + kb + c4 * 8);
      *(uint4*)&Bs[sp][row][(c4 ^ (row & 3)) * 8] = v;
    }
    __syncthreads();

    // capture h_old while its k-slice sits in LDS
    if (kb == kb_cap) {
      int cc = wn * 16 + c;   // col-within-32 of j = jb*32 + cc
      #pragma unroll
      for (int i = 0; i < 4; i++)
        #pragma unroll
        for (int reg = 0; reg < 4; reg++) {
          int m = wm * 64 + i * 16 + q * 4 + reg;
          int idx = (((cc >> 3) ^ (m & 3)) << 3) + (cc & 7);
          hold[i][reg] = h2f_(As[0][m][idx]) + h2f_(As[1][m][idx]) * INV4096;
        }
    }

    half8 af[4][2];
    #pragma unroll
    for (int i = 0; i < 4; i++) {
      int m = wm * 64 + i * 16 + c;
      af[i][0] = *(const half8*)&As[0][m][(q ^ (c & 3)) * 8];
      af[i][1] = *(const half8*)&As[1][m][(q ^ (c & 3)) * 8];
    }
    #pragma unroll
    for (int g = 0; g < 3; g++) {
      int rB = g * 32 + wn * 16 + c;
      half8 b0 = *(const half8*)&Bs[0][rB][(q ^ (c & 3)) * 8];
      half8 b1 = *(const half8*)&Bs[1][rB][(q ^ (c & 3)) * 8];
      #pragma unroll
      for (int i = 0; i < 4; i++) {
        accm[i][g] = __builtin_amdgcn_mfma_f32_16x16x32_f16(af[i][0], b0, accm[i][g], 0, 0, 0);
        accc[i][g] = __builtin_amdgcn_mfma_f32_16x16x32_f16(af[i][0], b1, accc[i][g], 0, 0, 0);
        accc[i][g] = __builtin_amdgcn_mfma_f32_16x16x32_f16(af[i][1], b0, accc[i][g], 0, 0, 0);
      }
    }
    __syncthreads();
  }

  // epilogue: gates + h update + fp16 2-split store
  {
    int j = jb * 32 + wn * 16 + c;
    float gyr = giy_k[j], gyz = giy_k[512 + j], gyn = giy_k[1024 + j];
    float w0r = W_ih[(size_t)j * 41];
    float w0z = W_ih[(size_t)(512 + j) * 41];
    float w0n = W_ih[(size_t)(1024 + j) * 41];
    float bhr = b_hh[j], bhz = b_hh[512 + j], bhn = b_hh[1024 + j];
    #pragma unroll
    for (int i = 0; i < 4; i++) {
      #pragma unroll
      for (int reg = 0; reg < 4; reg++) {
        int s = s0 + wm * 64 + i * 16 + q * 4 + reg;
        float tg = tgt_is_x ? tgt[HIST - 1] : tgt[s];
        size_t off = (size_t)s * 512 + j;
        float h_old = hold[i][reg];
        float ghr = accm[i][0][reg] + accc[i][0][reg] * INV4096;
        float ghz = accm[i][1][reg] + accc[i][1][reg] * INV4096;
        float ghn = accm[i][2][reg] + accc[i][2][reg] * INV4096;
        float gr = (gyr + w0r * tg) + (ghr + bhr);
        float gz = (gyz + w0z * tg) + (ghz + bhz);
        float gn_i = gyn + w0n * tg;
        float gn_h = ghn + bhn;
        float r_ = sigmoid_(gr);
        float z_ = sigmoid_(gz);
        float n_ = tanhf(gn_i + r_ * gn_h);
        float hn = (1.0f - z_) * n_ + z_ * h_old;
        unsigned short f0 = f2h_(hn);
        float r1 = (hn - h2f_(f0)) * 4096.0f;
        h2_out[off] = f0;
        h2_out[HPLANE + off] = f2h_(r1);
      }
    }
  }
}

// heads + student-t sampling (h from 2 fp16 planes). 128 blocks x 64 threads.
__global__ __launch_bounds__(64) void dec_head_kernel(
    const unsigned short* __restrict__ h2, const float* __restrict__ W_df,
    const float* __restrict__ b_df, const float* __restrict__ W_loc,
    const float* __restrict__ b_loc, const float* __restrict__ W_sc,
    const float* __restrict__ b_sc, const float* __restrict__ scale_p,
    float* __restrict__ tgt, float* __restrict__ out, int k) {
  #pragma clang fp contract(off)
  int s = blockIdx.x * 64 + threadIdx.x;
  size_t base = (size_t)s * 512;
  float adf = 0.f, alo = 0.f, asc = 0.f;
  for (int i = 0; i < 64; i++) {
    uint4 q0 = *(const uint4*)(h2 + base + 8 * i);
    uint4 q1 = *(const uint4*)(h2 + HPLANE + base + 8 * i);
    float x0 = h2f_((unsigned short)(q0.x & 0xffffu)) + h2f_((unsigned short)(q1.x & 0xffffu)) * INV4096;
    float x1 = h2f_((unsigned short)(q0.x >> 16))     + h2f_((unsigned short)(q1.x >> 16)) * INV4096;
    float x2 = h2f_((unsigned short)(q0.y & 0xffffu)) + h2f_((unsigned short)(q1.y & 0xffffu)) * INV4096;
    float x3 = h2f_((unsigned short)(q0.y >> 16))     + h2f_((unsigned short)(q1.y >> 16)) * INV4096;
    float x4 = h2f_((unsigned short)(q0.z & 0xffffu)) + h2f_((unsigned short)(q1.z & 0xffffu)) * INV4096;
    float x5 = h2f_((unsigned short)(q0.z >> 16))     + h2f_((unsigned short)(q1.z >> 16)) * INV4096;
    float x6 = h2f_((unsigned short)(q0.w & 0xffffu)) + h2f_((unsigned short)(q1.w & 0xffffu)) * INV4096;
    float x7 = h2f_((unsigned short)(q0.w >> 16))     + h2f_((unsigned short)(q1.w >> 16)) * INV4096;
    float4 wd0 = ((const float4*)W_df)[2 * i],  wd1 = ((const float4*)W_df)[2 * i + 1];
    float4 wl0 = ((const float4*)W_loc)[2 * i], wl1 = ((const float4*)W_loc)[2 * i + 1];
    float4 ws0 = ((const float4*)W_sc)[2 * i],  ws1 = ((const float4*)W_sc)[2 * i + 1];
    adf += x0 * wd0.x; adf += x1 * wd0.y; adf += x2 * wd0.z; adf += x3 * wd0.w;
    adf += x4 * wd1.x; adf += x5 * wd1.y; adf += x6 * wd1.z; adf += x7 * wd1.w;
    alo += x0 * wl0.x; alo += x1 * wl0.y; alo += x2 * wl0.z; alo += x3 * wl0.w;
    alo += x4 * wl1.x; alo += x5 * wl1.y; alo += x6 * wl1.z; alo += x7 * wl1.w;
    asc += x0 * ws0.x; asc += x1 * ws0.y; asc += x2 * ws0.z; asc += x3 * ws0.w;
    asc += x4 * ws1.x; asc += x5 * ws1.y; asc += x6 * ws1.z; asc += x7 * ws1.w;
  }
  float df = 2.0f + softplus_(adf + b_df[0]);
  float loc = alo + b_loc[0];
  float sc = softplus_(asc + b_sc[0]);
  float eps = sample_t_eps_(k, s, df);
  float smp = (loc + sc * eps) * scale_p[0];
  out[(size_t)s * PRED + k] = smp;
  tgt[s] = smp;
}

// ------------------------------- launcher ----------------------------------
extern "C" void kernel_launch(void* const* d_in, const int* in_sizes, int n_in,
                              void* d_out, int out_size, void* d_ws, size_t ws_size,
                              hipStream_t stream) {
  const float* x      = (const float*)d_in[0];
  const float* x_mark = (const float*)d_in[1];
  const float* y_mark = (const float*)d_in[2];
  const float* W_emb  = (const float*)d_in[4];
  const float* b_emb  = (const float*)d_in[5];
  const float* W_ih   = (const float*)d_in[6];
  const float* W_hh   = (const float*)d_in[7];
  const float* b_ih   = (const float*)d_in[8];
  const float* b_hh   = (const float*)d_in[9];
  const float* W_df   = (const float*)d_in[10];
  const float* b_df   = (const float*)d_in[11];
  const float* W_loc  = (const float*)d_in[12];
  const float* b_loc  = (const float*)d_in[13];
  const float* W_sc   = (const float*)d_in[14];
  const float* b_sc   = (const float*)d_in[15];
  float* out = (float*)d_out;

  float* w = (float*)d_ws;
  unsigned short* h2_a = (unsigned short*)(w);                 // 2*8192*512 sh
  unsigned short* h2_b = (unsigned short*)(w + 4194304);       // 2*8192*512 sh
  unsigned short* Wr   = (unsigned short*)(w + 8388608);       // 2*1536*512 sh
  float* enc_gi = w + 9175040;              // 336*1536
  float* giy    = w + 9691136;              // 48*1536
  float* tfe    = w + 9764864;              // 336*40
  float* emb_y  = w + 9778304;              // 48*40
  float* ghbuf  = w + 9780224;              // 2*1536
  float* h_T    = w + 9783296;              // 512
  unsigned short* sT = (unsigned short*)(w + 9783808);  // 2*512 sh
  float* tgt    = w + 9784320;              // 8192
  float* scale_p = w + 9792512;             // 1
  unsigned* flags = (unsigned*)(w + 9792516);  // 48*16 ints

  prep_kernel<<<1, 256, 0, stream>>>(x, x_mark, y_mark, W_emb, b_emb,
                                     scale_p, tfe, emb_y, flags);
  enc_gi_kernel<<<HIST, 256, 0, stream>>>(x, tfe, W_ih, b_ih, scale_p, enc_gi);
  giy_kernel<<<PRED, 256, 0, stream>>>(emb_y, W_ih, b_ih, giy);
  wsplit_kernel<<<1536, 256, 0, stream>>>(W_hh, Wr);
  enc_gru_kernel<<<ENC_BLOCKS, 256, 0, stream>>>(enc_gi, W_hh, b_hh, ghbuf,
                                                 flags, h_T);
  hsplit_kernel<<<1, 256, 0, stream>>>(h_T, sT);
  h2bcast_kernel<<<S_N, 128, 0, stream>>>(sT, h2_a);

  for (int k = 0; k < PRED; k++) {
    const unsigned short* h_in = (k % 2 == 0) ? h2_a : h2_b;
    unsigned short* h_o = (k % 2 == 0) ? h2_b : h2_a;
    dec_gru_mfma<<<1024, 256, 0, stream>>>(
        h_in, Wr, giy + (size_t)k * 1536, b_hh, W_ih,
        (k == 0) ? x : tgt, (k == 0) ? 1 : 0, h_o);
    dec_head_kernel<<<S_N / 64, 64, 0, stream>>>(
        h_o, W_df, b_df, W_loc, b_loc, W_sc, b_sc, scale_p, tgt, out, k);
  }
}

// Round 6
// 5795.451 us; speedup vs baseline: 1.9033x; 1.1265x over previous
//
#include <hip/hip_runtime.h>
#include <cmath>

// ---------------------------------------------------------------------------
// DeepAR sampling on MI355X. Round 6:
//  - dec_head: 128 waves -> 1024 waves (8 samples/wave): wave-cooperative
//    dot (lane partials + shfl butterfly, deterministic) + 8-lane-parallel
//    rejection sampling. Was 8192 threads @ 0.125% occupancy, latency-bound.
//  - dec_gru: B-frags direct global->reg from L2 (prefetched 1 K-iter ahead,
//    4 lanes share each 64B line), A double-buffered in LDS -> 1 barrier/iter,
//    LDS traffic 84 -> 48 KB/iter. MFMA order unchanged (gh bit-identical).
//  - encoder unchanged (round-3 flag barrier, 1.29 ms).
// NOTE: head dot reorder re-rolls the rejection-flip lottery; absmax may
// move off 1.492188 (expected flips ~0.6 across 590k decisions).
// ---------------------------------------------------------------------------

#define JAX_PARTITIONABLE 1

#define HIDDEN 512
#define EMB 40
#define HIST 336
#define PRED 48
#define S_N 8192
#define ENC_BLOCKS 48

#define HPLANE (8192 * 512)     // shorts per h split plane
#define WPLANE (1536 * 512)     // shorts per W split plane
#define INV4096 (1.0f / 4096.0f)

typedef __attribute__((ext_vector_type(8))) _Float16 half8;
typedef __attribute__((ext_vector_type(4))) float f32x4;

// ------------------------------- threefry ----------------------------------
struct KeyPair { unsigned a, b; };

__device__ __forceinline__ unsigned rotl32_(unsigned v, unsigned s) {
  return (v << s) | (v >> (32u - s));
}

__device__ __forceinline__ KeyPair tf2x32(KeyPair k, unsigned x0, unsigned x1) {
  unsigned ks0 = k.a, ks1 = k.b, ks2 = ks0 ^ ks1 ^ 0x1BD11BDAu;
  x0 += ks0; x1 += ks1;
#define TF_R(r) { x0 += x1; x1 = rotl32_(x1, r); x1 ^= x0; }
  TF_R(13u) TF_R(15u) TF_R(26u) TF_R(6u)  x0 += ks1; x1 += ks2 + 1u;
  TF_R(17u) TF_R(29u) TF_R(16u) TF_R(24u) x0 += ks2; x1 += ks0 + 2u;
  TF_R(13u) TF_R(15u) TF_R(26u) TF_R(6u)  x0 += ks0; x1 += ks1 + 3u;
  TF_R(17u) TF_R(29u) TF_R(16u) TF_R(24u) x0 += ks1; x1 += ks2 + 4u;
  TF_R(13u) TF_R(15u) TF_R(26u) TF_R(6u)  x0 += ks2; x1 += ks0 + 5u;
#undef TF_R
  KeyPair r; r.a = x0; r.b = x1; return r;
}

__device__ __forceinline__ void split2_(KeyPair key, KeyPair& r0, KeyPair& r1) {
#if JAX_PARTITIONABLE
  r0 = tf2x32(key, 0u, 0u);
  r1 = tf2x32(key, 0u, 1u);
#else
  KeyPair p0 = tf2x32(key, 0u, 2u);
  KeyPair p1 = tf2x32(key, 1u, 3u);
  r0.a = p0.a; r0.b = p1.a;
  r1.a = p0.b; r1.b = p1.b;
#endif
}

__device__ __forceinline__ void split3_(KeyPair key, KeyPair& r0, KeyPair& r1, KeyPair& r2) {
#if JAX_PARTITIONABLE
  r0 = tf2x32(key, 0u, 0u);
  r1 = tf2x32(key, 0u, 1u);
  r2 = tf2x32(key, 0u, 2u);
#else
  KeyPair p0 = tf2x32(key, 0u, 3u);
  KeyPair p1 = tf2x32(key, 1u, 4u);
  KeyPair p2 = tf2x32(key, 2u, 5u);
  r0.a = p0.a; r0.b = p1.a;
  r1.a = p2.a; r1.b = p0.b;
  r2.a = p1.b; r2.b = p2.b;
#endif
}

__device__ __forceinline__ unsigned scalar_bits_(KeyPair key) {
#if JAX_PARTITIONABLE
  KeyPair p = tf2x32(key, 0u, 0u);
  return p.a ^ p.b;
#else
  return tf2x32(key, 0u, 0u).a;
#endif
}

__device__ __forceinline__ unsigned batch_bits_8192_(KeyPair key, int s) {
#if JAX_PARTITIONABLE
  KeyPair p = tf2x32(key, 0u, (unsigned)s);
  return p.a ^ p.b;
#else
  if (s < 4096) return tf2x32(key, (unsigned)s, (unsigned)(4096 + s)).a;
  return tf2x32(key, (unsigned)(s - 4096), (unsigned)s).b;
#endif
}

__device__ __forceinline__ KeyPair subkey_of_8192_(KeyPair key, int s) {
#if JAX_PARTITIONABLE
  return tf2x32(key, 0u, (unsigned)s);
#else
  KeyPair r;
  if (s < 4096) {
    r.a = tf2x32(key, (unsigned)(2 * s),     (unsigned)(8192 + 2 * s)).a;
    r.b = tf2x32(key, (unsigned)(2 * s + 1), (unsigned)(8192 + 2 * s + 1)).a;
  } else {
    int m = 2 * s - 8192;
    r.a = tf2x32(key, (unsigned)m,       (unsigned)(m + 8192)).b;
    r.b = tf2x32(key, (unsigned)(m + 1), (unsigned)(m + 1 + 8192)).b;
  }
  return r;
#endif
}

// ------------------------- fp32 numerics (XLA-matched) ---------------------
__device__ __forceinline__ float acc_logf_(float x) {
  return (float)log((double)x);
}
__device__ __forceinline__ float acc_expf_(float x) {
  return (float)exp((double)x);
}

__device__ __forceinline__ float bits_to_uniform01_(unsigned bits) {
  return __uint_as_float((bits >> 9) | 0x3F800000u) - 1.0f;
}

__device__ __forceinline__ float xla_log1pf_(float t) {
  #pragma clang fp contract(off)
  float small_ = (1.0f + (-0.5f) * t) * t;
  float large_ = acc_logf_(t + 1.0f);
  return (fabsf(t) < 1e-4f) ? small_ : large_;
}

__device__ float xla_erfinv_(float x) {
  #pragma clang fp contract(off)
  float w = -xla_log1pf_(-(x * x));
  float p;
  if (w < 5.0f) {
    float ww = w - 2.5f;
    p = 2.81022636e-08f;
    p = 3.43273939e-07f + p * ww;
    p = -3.5233877e-06f + p * ww;
    p = -4.39150654e-06f + p * ww;
    p = 0.00021858087f + p * ww;
    p = -0.00125372503f + p * ww;
    p = -0.00417768164f + p * ww;
    p = 0.246640727f + p * ww;
    p = 1.50140941f + p * ww;
  } else {
    float ww = sqrtf(w) - 3.0f;
    p = -0.000200214257f;
    p = 0.000100950558f + p * ww;
    p = 0.00134934322f + p * ww;
    p = -0.00367342844f + p * ww;
    p = 0.00573950773f + p * ww;
    p = -0.0076224613f + p * ww;
    p = 0.00943887047f + p * ww;
    p = 1.00167406f + p * ww;
    p = 2.83297682f + p * ww;
  }
  return p * x;
}

__device__ float bits_to_normal_(unsigned bits) {
  #pragma clang fp contract(off)
  const float lo = __uint_as_float(0xBF7FFFFFu);
  float f = bits_to_uniform01_(bits);
  float u = f * 2.0f + lo;
  u = fmaxf(lo, u);
  return __uint_as_float(0x3FB504F3u) * xla_erfinv_(u);
}

__device__ __forceinline__ float softplus_(float x) {
  #pragma clang fp contract(off)
  float amax = fmaxf(x, 0.0f);
  float e = acc_expf_(-fabsf(x));
  return amax + xla_log1pf_(e);
}

__device__ __forceinline__ float sigmoid_(float v) { return 1.0f / (1.0f + expf(-v)); }

// fp16 split helpers (round-to-nearest-even via cast)
__device__ __forceinline__ unsigned short f2h_(float f) {
  _Float16 h = (_Float16)f;
  return __builtin_bit_cast(unsigned short, h);
}
__device__ __forceinline__ float h2f_(unsigned short b) {
  return (float)__builtin_bit_cast(_Float16, b);
}

// ------------------------- gamma / student-t sampler -----------------------
__device__ float gamma_sample_(KeyPair gkey, float alpha) {
  #pragma clang fp contract(off)
  const float third = 0.33333334f;
  float d = alpha - third;
  float c = third / sqrtf(d);
  KeyPair key, boost_sub;
  split2_(gkey, key, boost_sub);
  (void)boost_sub;
  float X = 0.0f, V = 1.0f, U = 2.0f;
  for (int guard = 0; guard < 1024; guard++) {
    float X2 = X * X;
    float sq = 1.0f - 0.0331f * (X2 * X2);
    bool cont = false;
    if (U >= sq) {
      float lhs = acc_logf_(U);
      float rhs = (X * 0.5f) + (d * ((1.0f - V) + acc_logf_(V)));
      cont = (lhs >= rhs);
    }
    if (!cont) break;
    KeyPair nkey, xkey, Ukey;
    split3_(key, nkey, xkey, Ukey);
    key = nkey;
    float x, v;
    KeyPair kk = xkey;
    do {
      KeyPair knew, sub;
      split2_(kk, knew, sub);
      kk = knew;
      x = bits_to_normal_(scalar_bits_(sub));
      v = 1.0f + x * c;
    } while (v <= 0.0f);
    X = x * x;
    V = (v * v) * v;
    U = bits_to_uniform01_(scalar_bits_(Ukey));
  }
  return d * V;
}

__device__ float sample_t_eps_(int k, int s, float df) {
  #pragma clang fp contract(off)
  KeyPair base; base.a = 0u; base.b = 42u;
  KeyPair tkey = tf2x32(base, 0u, (unsigned)k);
  KeyPair key_n, key_g;
  split2_(tkey, key_n, key_g);
  float n = bits_to_normal_(batch_bits_8192_(key_n, s));
  KeyPair gkey = subkey_of_8192_(key_g, s);
  float half_df = df * 0.5f;
  float g = gamma_sample_(gkey, half_df);
  return n * sqrtf(half_df / g);
}

// ------------------------------- kernels -----------------------------------

__global__ __launch_bounds__(256) void prep_kernel(
    const float* __restrict__ x, const float* __restrict__ x_mark,
    const float* __restrict__ y_mark, const float* __restrict__ W_emb,
    const float* __restrict__ b_emb, float* __restrict__ scale_p,
    float* __restrict__ tfe, float* __restrict__ emb_y,
    unsigned* __restrict__ flags) {
  int tid = threadIdx.x;
  if (tid == 0) {
    float s = 0.0f;
    for (int t = 0; t < HIST; t++) s += fabsf(x[t]);
    float m = s / 336.0f;
    scale_p[0] = fmaxf(m, 1e-5f);
  }
  for (int i = tid; i < ENC_BLOCKS * 16; i += 256) flags[i] = 0u;
  for (int idx = tid; idx < HIST * EMB; idx += 256) {
    int t = idx / EMB, e = idx % EMB;
    float a = b_emb[e];
    for (int f = 0; f < 4; f++) a += x_mark[t * 4 + f] * W_emb[e * 4 + f];
    tfe[idx] = a;
  }
  for (int idx = tid; idx < PRED * EMB; idx += 256) {
    int kk = idx / EMB, e = idx % EMB;
    float a = b_emb[e];
    for (int f = 0; f < 4; f++) a += y_mark[kk * 4 + f] * W_emb[e * 4 + f];
    emb_y[idx] = a;
  }
}

__global__ __launch_bounds__(256) void enc_gi_kernel(
    const float* __restrict__ x, const float* __restrict__ tfe,
    const float* __restrict__ W_ih, const float* __restrict__ b_ih,
    const float* __restrict__ scale_p, float* __restrict__ enc_gi) {
  __shared__ float fe[EMB];
  __shared__ float xs_s;
  int t = blockIdx.x;
  int tid = threadIdx.x;
  if (tid < EMB) fe[tid] = tfe[t * EMB + tid];
  if (tid == 0) xs_s = x[t] / scale_p[0];
  __syncthreads();
  float xs = xs_s;
  for (int r = tid; r < 3 * HIDDEN; r += 256) {
    const float* wr = W_ih + (size_t)r * 41;
    float a = b_ih[r] + wr[0] * xs;
    #pragma unroll
    for (int e = 0; e < EMB; e++) a += wr[1 + e] * fe[e];
    enc_gi[(size_t)t * 1536 + r] = a;
  }
}

__global__ __launch_bounds__(256) void giy_kernel(
    const float* __restrict__ emb_y, const float* __restrict__ W_ih,
    const float* __restrict__ b_ih, float* __restrict__ giy) {
  __shared__ float fe[EMB];
  int k = blockIdx.x;
  int tid = threadIdx.x;
  if (tid < EMB) fe[tid] = emb_y[k * EMB + tid];
  __syncthreads();
  for (int r = tid; r < 3 * HIDDEN; r += 256) {
    const float* wr = W_ih + (size_t)r * 41;
    float a = b_ih[r];
    #pragma unroll
    for (int e = 0; e < EMB; e++) a += wr[1 + e] * fe[e];
    giy[(size_t)k * 1536 + r] = a;
  }
}

// W_hh -> 2 fp16 split planes: Wr[sp][jb*96 + g*32 + jl][k], row = g*512+jb*32+jl
__global__ __launch_bounds__(256) void wsplit_kernel(
    const float* __restrict__ W_hh, unsigned short* __restrict__ Wr) {
  int row = blockIdx.x;                 // 0..1535
  int g = row >> 9;
  int jg = row & 511;
  int jb = jg >> 5, jl = jg & 31;
  size_t dst = ((size_t)jb * 96 + g * 32 + jl) * 512;
  for (int k = threadIdx.x; k < 512; k += 256) {
    float w = W_hh[(size_t)row * 512 + k];
    unsigned short g0 = f2h_(w);
    float r1 = (w - h2f_(g0)) * 4096.0f;
    unsigned short g1 = f2h_(r1);
    Wr[dst + k] = g0;
    Wr[WPLANE + dst + k] = g1;
  }
}

// split h_T (512) into sT[2][512] fp16 planes
__global__ __launch_bounds__(256) void hsplit_kernel(
    const float* __restrict__ h_T, unsigned short* __restrict__ sT) {
  int i = threadIdx.x;
  for (int j = i; j < 512; j += 256) {
    float v = h_T[j];
    unsigned short f0 = f2h_(v);
    float r1 = (v - h2f_(f0)) * 4096.0f;
    sT[j] = f0;
    sT[512 + j] = f2h_(r1);
  }
}

// broadcast sT rows into h2[2][8192][512]
__global__ __launch_bounds__(128) void h2bcast_kernel(
    const unsigned short* __restrict__ sT, unsigned short* __restrict__ h2) {
  int row = blockIdx.x;
  int tid = threadIdx.x;
  int sp = tid >> 6, c = tid & 63;
  ((uint4*)(h2 + (size_t)sp * HPLANE + (size_t)row * 512))[c] =
      ((const uint4*)(sT + sp * 512))[c];
}

// persistent encoder GRU; round-3 flag-array grid barrier
__global__ __launch_bounds__(256) void enc_gru_kernel(
    const float* __restrict__ enc_gi, const float* __restrict__ W_hh,
    const float* __restrict__ b_hh, float* __restrict__ ghbuf,
    unsigned* __restrict__ flags, float* __restrict__ h_T) {
  __shared__ __align__(16) float hs[HIDDEN];
  int tid = threadIdx.x;
  int gtid = blockIdx.x * 256 + tid;
  int row = gtid >> 3;
  int sub = gtid & 7;

  float w[64];
  const float* wp = W_hh + (size_t)row * HIDDEN + sub * 64;
  #pragma unroll
  for (int i = 0; i < 16; i++) {
    float4 v = *(const float4*)(wp + 4 * i);
    w[4 * i + 0] = v.x; w[4 * i + 1] = v.y; w[4 * i + 2] = v.z; w[4 * i + 3] = v.w;
  }
  if (tid < 128) *(float4*)&hs[tid * 4] = make_float4(0.f, 0.f, 0.f, 0.f);
  float bhr0 = b_hh[tid],       bhz0 = b_hh[512 + tid],  bhn0 = b_hh[1024 + tid];
  float bhr1 = b_hh[256 + tid], bhz1 = b_hh[768 + tid],  bhn1 = b_hh[1280 + tid];
  __syncthreads();

  for (int t = 0; t < HIST; t++) {
    float p = 0.0f;
    const float4* hv = (const float4*)&hs[sub * 64];
    #pragma unroll
    for (int i = 0; i < 16; i++) {
      float4 v = hv[i];
      p += w[4 * i + 0] * v.x + w[4 * i + 1] * v.y +
           w[4 * i + 2] * v.z + w[4 * i + 3] * v.w;
    }
    p += __shfl_xor(p, 1, 64);
    p += __shfl_xor(p, 2, 64);
    p += __shfl_xor(p, 4, 64);
    int par = t & 1;
    if (sub == 0)
      __hip_atomic_store(&ghbuf[par * 1536 + row], p, __ATOMIC_RELAXED,
                         __HIP_MEMORY_SCOPE_AGENT);
    __syncthreads();
    if (tid == 0)
      __hip_atomic_store(&flags[blockIdx.x * 16], (unsigned)(t + 1),
                         __ATOMIC_RELEASE, __HIP_MEMORY_SCOPE_AGENT);
    if (tid < ENC_BLOCKS) {
      while (__hip_atomic_load(&flags[tid * 16], __ATOMIC_ACQUIRE,
                               __HIP_MEMORY_SCOPE_AGENT) < (unsigned)(t + 1))
        __builtin_amdgcn_s_sleep(1);
    }
    __syncthreads();
    float hn0, hn1;
    {
      int j = tid;
      float ghr = __hip_atomic_load(&ghbuf[par * 1536 + j], __ATOMIC_RELAXED, __HIP_MEMORY_SCOPE_AGENT);
      float ghz = __hip_atomic_load(&ghbuf[par * 1536 + 512 + j], __ATOMIC_RELAXED, __HIP_MEMORY_SCOPE_AGENT);
      float ghn = __hip_atomic_load(&ghbuf[par * 1536 + 1024 + j], __ATOMIC_RELAXED, __HIP_MEMORY_SCOPE_AGENT);
      float gir = enc_gi[(size_t)t * 1536 + j];
      float giz = enc_gi[(size_t)t * 1536 + 512 + j];
      float gin = enc_gi[(size_t)t * 1536 + 1024 + j];
      float r = sigmoid_(gir + (ghr + bhr0));
      float z = sigmoid_(giz + (ghz + bhz0));
      float n = tanhf(gin + r * (ghn + bhn0));
      hn0 = (1.0f - z) * n + z * hs[j];
    }
    {
      int j = tid + 256;
      float ghr = __hip_atomic_load(&ghbuf[par * 1536 + j], __ATOMIC_RELAXED, __HIP_MEMORY_SCOPE_AGENT);
      float ghz = __hip_atomic_load(&ghbuf[par * 1536 + 512 + j], __ATOMIC_RELAXED, __HIP_MEMORY_SCOPE_AGENT);
      float ghn = __hip_atomic_load(&ghbuf[par * 1536 + 1024 + j], __ATOMIC_RELAXED, __HIP_MEMORY_SCOPE_AGENT);
      float gir = enc_gi[(size_t)t * 1536 + j];
      float giz = enc_gi[(size_t)t * 1536 + 512 + j];
      float gin = enc_gi[(size_t)t * 1536 + 1024 + j];
      float r = sigmoid_(gir + (ghr + bhr1));
      float z = sigmoid_(giz + (ghz + bhz1));
      float n = tanhf(gin + r * (ghn + bhn1));
      hn1 = (1.0f - z) * n + z * hs[j];
    }
    hs[tid] = hn0;
    hs[tid + 256] = hn1;
    __syncthreads();
  }
  if (blockIdx.x == 0 && tid < 128)
    *(float4*)&h_T[tid * 4] = *(float4*)&hs[tid * 4];
}

// ---------------------------------------------------------------------------
// Decoder GRU step via fp16 MFMA, 2-split x 3 products.
// A double-buffered in LDS (1 barrier/iter); B-frags direct global->reg,
// prefetched one K-iter ahead. MFMA order identical to round 5.
// ---------------------------------------------------------------------------
__global__ __launch_bounds__(256, 2) void dec_gru_mfma(
    const unsigned short* __restrict__ h2_in,   // [2][8192][512] fp16
    const unsigned short* __restrict__ Wr,      // [2][16 jb][96][512] fp16
    const float* __restrict__ giy_k, const float* __restrict__ b_hh,
    const float* __restrict__ W_ih, const float* __restrict__ tgt,
    int tgt_is_x, unsigned short* __restrict__ h2_out) {
  __shared__ unsigned short As[2][2][128][32];   // [buf][plane][row][col]
  int b_ = blockIdx.x;
  int xcd = b_ & 7, slot = b_ >> 3;          // slot 0..127
  int mb = xcd * 8 + (slot & 7);             // 0..63
  int jb = slot >> 3;                        // 0..15
  int tid = threadIdx.x;
  int lane = tid & 63;
  int wave = tid >> 6;
  int wm = wave >> 1, wn = wave & 1;
  int s0 = mb * 128;
  int q = lane >> 4, c = lane & 15;

  f32x4 accm[4][3], accc[4][3];
  #pragma unroll
  for (int i = 0; i < 4; i++)
    #pragma unroll
    for (int g = 0; g < 3; g++) {
      accm[i][g] = (f32x4){0.f, 0.f, 0.f, 0.f};
      accc[i][g] = (f32x4){0.f, 0.f, 0.f, 0.f};
    }

  float hold[4][4];
  #pragma unroll
  for (int i = 0; i < 4; i++)
    #pragma unroll
    for (int r = 0; r < 4; r++) hold[i][r] = 0.f;

  // per-thread A staging map (4 chunks covering 2 planes x 128 rows x 32 cols)
  int asp[4], arow[4], acol[4];
  #pragma unroll
  for (int r = 0; r < 4; r++) {
    int a = r * 256 + tid;
    asp[r] = a >> 9;
    int rem = a & 511;
    arow[r] = rem >> 2;
    acol[r] = rem & 3;
  }

  // B-frag base address (row jb*96 + g*32 + wn*16 + c, col chunk q)
  const unsigned short* Bbase =
      Wr + ((size_t)jb * 96 + wn * 16 + c) * 512 + q * 8;

  // initial stage A (kb=0) into buffer 0
  #pragma unroll
  for (int r = 0; r < 4; r++) {
    uint4 v = *(const uint4*)(h2_in + (size_t)asp[r] * HPLANE +
                              (size_t)(s0 + arow[r]) * 512 + acol[r] * 8);
    *(uint4*)&As[0][asp[r]][arow[r]][(acol[r] ^ (arow[r] & 3)) * 8] = v;
  }
  // initial B (kb=0)
  half8 Bcur[3][2];
  #pragma unroll
  for (int g = 0; g < 3; g++) {
    Bcur[g][0] = *(const half8*)(Bbase + (size_t)g * 32 * 512);
    Bcur[g][1] = *(const half8*)(Bbase + WPLANE + (size_t)g * 32 * 512);
  }
  __syncthreads();

  int cur = 0;
  for (int kbi = 0; kbi < 16; kbi++) {
    int kb = kbi * 32;
    // prefetch next A + B
    uint4 Areg[4];
    half8 Bn[3][2];
    if (kbi < 15) {
      #pragma unroll
      for (int r = 0; r < 4; r++)
        Areg[r] = *(const uint4*)(h2_in + (size_t)asp[r] * HPLANE +
                                  (size_t)(s0 + arow[r]) * 512 + kb + 32 +
                                  acol[r] * 8);
      #pragma unroll
      for (int g = 0; g < 3; g++) {
        Bn[g][0] = *(const half8*)(Bbase + (size_t)g * 32 * 512 + kb + 32);
        Bn[g][1] = *(const half8*)(Bbase + WPLANE + (size_t)g * 32 * 512 + kb + 32);
      }
    }
    // capture h_old while its k-slice sits in LDS
    if (kbi == jb) {
      int cc = wn * 16 + c;
      #pragma unroll
      for (int i = 0; i < 4; i++)
        #pragma unroll
        for (int reg = 0; reg < 4; reg++) {
          int m = wm * 64 + i * 16 + q * 4 + reg;
          int idx = (((cc >> 3) ^ (m & 3)) << 3) + (cc & 7);
          hold[i][reg] = h2f_(As[cur][0][m][idx]) +
                         h2f_(As[cur][1][m][idx]) * INV4096;
        }
    }
    // compute (MFMA order identical to round 5: per (i,g): m; c:a0b1; c:a1b0)
    #pragma unroll
    for (int i = 0; i < 4; i++) {
      int m = wm * 64 + i * 16 + c;
      half8 a0 = *(const half8*)&As[cur][0][m][(q ^ (c & 3)) * 8];
      half8 a1 = *(const half8*)&As[cur][1][m][(q ^ (c & 3)) * 8];
      #pragma unroll
      for (int g = 0; g < 3; g++) {
        accm[i][g] = __builtin_amdgcn_mfma_f32_16x16x32_f16(a0, Bcur[g][0], accm[i][g], 0, 0, 0);
        accc[i][g] = __builtin_amdgcn_mfma_f32_16x16x32_f16(a0, Bcur[g][1], accc[i][g], 0, 0, 0);
        accc[i][g] = __builtin_amdgcn_mfma_f32_16x16x32_f16(a1, Bcur[g][0], accc[i][g], 0, 0, 0);
      }
    }
    // store prefetched A into the other buffer
    if (kbi < 15) {
      #pragma unroll
      for (int r = 0; r < 4; r++)
        *(uint4*)&As[cur ^ 1][asp[r]][arow[r]][(acol[r] ^ (arow[r] & 3)) * 8] =
            Areg[r];
      #pragma unroll
      for (int g = 0; g < 3; g++) {
        Bcur[g][0] = Bn[g][0];
        Bcur[g][1] = Bn[g][1];
      }
    }
    __syncthreads();
    cur ^= 1;
  }

  // epilogue: gates + h update + fp16 2-split store
  {
    int j = jb * 32 + wn * 16 + c;
    float gyr = giy_k[j], gyz = giy_k[512 + j], gyn = giy_k[1024 + j];
    float w0r = W_ih[(size_t)j * 41];
    float w0z = W_ih[(size_t)(512 + j) * 41];
    float w0n = W_ih[(size_t)(1024 + j) * 41];
    float bhr = b_hh[j], bhz = b_hh[512 + j], bhn = b_hh[1024 + j];
    #pragma unroll
    for (int i = 0; i < 4; i++) {
      #pragma unroll
      for (int reg = 0; reg < 4; reg++) {
        int s = s0 + wm * 64 + i * 16 + q * 4 + reg;
        float tg = tgt_is_x ? tgt[HIST - 1] : tgt[s];
        size_t off = (size_t)s * 512 + j;
        float h_old = hold[i][reg];
        float ghr = accm[i][0][reg] + accc[i][0][reg] * INV4096;
        float ghz = accm[i][1][reg] + accc[i][1][reg] * INV4096;
        float ghn = accm[i][2][reg] + accc[i][2][reg] * INV4096;
        float gr = (gyr + w0r * tg) + (ghr + bhr);
        float gz = (gyz + w0z * tg) + (ghz + bhz);
        float gn_i = gyn + w0n * tg;
        float gn_h = ghn + bhn;
        float r_ = sigmoid_(gr);
        float z_ = sigmoid_(gz);
        float n_ = tanhf(gn_i + r_ * gn_h);
        float hn = (1.0f - z_) * n_ + z_ * h_old;
        unsigned short f0 = f2h_(hn);
        float r1 = (hn - h2f_(f0)) * 4096.0f;
        h2_out[off] = f0;
        h2_out[HPLANE + off] = f2h_(r1);
      }
    }
  }
}

// ---------------------------------------------------------------------------
// heads + student-t sampling. 1024 blocks x 64 threads; each wave handles
// 8 samples: cooperative dot (lane partials + shfl butterfly) then
// 8-lane-parallel rejection sampling. XCD-swizzled to follow dec_gru's h2.
// ---------------------------------------------------------------------------
__global__ __launch_bounds__(64) void dec_head_kernel(
    const unsigned short* __restrict__ h2, const float* __restrict__ W_df,
    const float* __restrict__ b_df, const float* __restrict__ W_loc,
    const float* __restrict__ b_loc, const float* __restrict__ W_sc,
    const float* __restrict__ b_sc, const float* __restrict__ scale_p,
    float* __restrict__ tgt, float* __restrict__ out, int k) {
  #pragma clang fp contract(off)
  int b_ = blockIdx.x;
  int xcd = b_ & 7, slot = b_ >> 3;          // slot 0..127
  int s0 = (xcd * 128 + slot) * 8;           // 8 samples per wave
  int lane = threadIdx.x;

  // per-lane W columns (8 elems each head)
  float wd[8], wl[8], ws[8];
  {
    float4 a0 = ((const float4*)W_df)[lane * 2];
    float4 a1 = ((const float4*)W_df)[lane * 2 + 1];
    wd[0] = a0.x; wd[1] = a0.y; wd[2] = a0.z; wd[3] = a0.w;
    wd[4] = a1.x; wd[5] = a1.y; wd[6] = a1.z; wd[7] = a1.w;
    float4 l0 = ((const float4*)W_loc)[lane * 2];
    float4 l1 = ((const float4*)W_loc)[lane * 2 + 1];
    wl[0] = l0.x; wl[1] = l0.y; wl[2] = l0.z; wl[3] = l0.w;
    wl[4] = l1.x; wl[5] = l1.y; wl[6] = l1.z; wl[7] = l1.w;
    float4 s0v = ((const float4*)W_sc)[lane * 2];
    float4 s1v = ((const float4*)W_sc)[lane * 2 + 1];
    ws[0] = s0v.x; ws[1] = s0v.y; ws[2] = s0v.z; ws[3] = s0v.w;
    ws[4] = s1v.x; ws[5] = s1v.y; ws[6] = s1v.z; ws[7] = s1v.w;
  }

  float adf = 0.f, alo = 0.f, asc = 0.f;   // captured per-lane for its sample
  #pragma unroll
  for (int i = 0; i < 8; i++) {
    size_t base = (size_t)(s0 + i) * 512 + lane * 8;
    uint4 q0 = *(const uint4*)(h2 + base);
    uint4 q1 = *(const uint4*)(h2 + HPLANE + base);
    float xs[8];
    xs[0] = h2f_((unsigned short)(q0.x & 0xffffu)) + h2f_((unsigned short)(q1.x & 0xffffu)) * INV4096;
    xs[1] = h2f_((unsigned short)(q0.x >> 16))     + h2f_((unsigned short)(q1.x >> 16)) * INV4096;
    xs[2] = h2f_((unsigned short)(q0.y & 0xffffu)) + h2f_((unsigned short)(q1.y & 0xffffu)) * INV4096;
    xs[3] = h2f_((unsigned short)(q0.y >> 16))     + h2f_((unsigned short)(q1.y >> 16)) * INV4096;
    xs[4] = h2f_((unsigned short)(q0.z & 0xffffu)) + h2f_((unsigned short)(q1.z & 0xffffu)) * INV4096;
    xs[5] = h2f_((unsigned short)(q0.z >> 16))     + h2f_((unsigned short)(q1.z >> 16)) * INV4096;
    xs[6] = h2f_((unsigned short)(q0.w & 0xffffu)) + h2f_((unsigned short)(q1.w & 0xffffu)) * INV4096;
    xs[7] = h2f_((unsigned short)(q0.w >> 16))     + h2f_((unsigned short)(q1.w >> 16)) * INV4096;
    float pdf = 0.f, plo = 0.f, psc = 0.f;
    #pragma unroll
    for (int e = 0; e < 8; e++) {
      pdf += xs[e] * wd[e];
      plo += xs[e] * wl[e];
      psc += xs[e] * ws[e];
    }
    #pragma unroll
    for (int off = 1; off < 64; off <<= 1) {
      pdf += __shfl_xor(pdf, off, 64);
      plo += __shfl_xor(plo, off, 64);
      psc += __shfl_xor(psc, off, 64);
    }
    if (lane == i) { adf = pdf; alo = plo; asc = psc; }
  }

  if (lane < 8) {
    int s = s0 + lane;
    float df = 2.0f + softplus_(adf + b_df[0]);
    float loc = alo + b_loc[0];
    float sc = softplus_(asc + b_sc[0]);
    float eps = sample_t_eps_(k, s, df);
    float smp = (loc + sc * eps) * scale_p[0];
    out[(size_t)s * PRED + k] = smp;
    tgt[s] = smp;
  }
}

// ------------------------------- launcher ----------------------------------
extern "C" void kernel_launch(void* const* d_in, const int* in_sizes, int n_in,
                              void* d_out, int out_size, void* d_ws, size_t ws_size,
                              hipStream_t stream) {
  const float* x      = (const float*)d_in[0];
  const float* x_mark = (const float*)d_in[1];
  const float* y_mark = (const float*)d_in[2];
  const float* W_emb  = (const float*)d_in[4];
  const float* b_emb  = (const float*)d_in[5];
  const float* W_ih   = (const float*)d_in[6];
  const float* W_hh   = (const float*)d_in[7];
  const float* b_ih   = (const float*)d_in[8];
  const float* b_hh   = (const float*)d_in[9];
  const float* W_df   = (const float*)d_in[10];
  const float* b_df   = (const float*)d_in[11];
  const float* W_loc  = (const float*)d_in[12];
  const float* b_loc  = (const float*)d_in[13];
  const float* W_sc   = (const float*)d_in[14];
  const float* b_sc   = (const float*)d_in[15];
  float* out = (float*)d_out;

  float* w = (float*)d_ws;
  unsigned short* h2_a = (unsigned short*)(w);                 // 2*8192*512 sh
  unsigned short* h2_b = (unsigned short*)(w + 4194304);       // 2*8192*512 sh
  unsigned short* Wr   = (unsigned short*)(w + 8388608);       // 2*1536*512 sh
  float* enc_gi = w + 9175040;              // 336*1536
  float* giy    = w + 9691136;              // 48*1536
  float* tfe    = w + 9764864;              // 336*40
  float* emb_y  = w + 9778304;              // 48*40
  float* ghbuf  = w + 9780224;              // 2*1536
  float* h_T    = w + 9783296;              // 512
  unsigned short* sT = (unsigned short*)(w + 9783808);  // 2*512 sh
  float* tgt    = w + 9784320;              // 8192
  float* scale_p = w + 9792512;             // 1
  unsigned* flags = (unsigned*)(w + 9792516);  // 48*16 ints

  prep_kernel<<<1, 256, 0, stream>>>(x, x_mark, y_mark, W_emb, b_emb,
                                     scale_p, tfe, emb_y, flags);
  enc_gi_kernel<<<HIST, 256, 0, stream>>>(x, tfe, W_ih, b_ih, scale_p, enc_gi);
  giy_kernel<<<PRED, 256, 0, stream>>>(emb_y, W_ih, b_ih, giy);
  wsplit_kernel<<<1536, 256, 0, stream>>>(W_hh, Wr);
  enc_gru_kernel<<<ENC_BLOCKS, 256, 0, stream>>>(enc_gi, W_hh, b_hh, ghbuf,
                                                 flags, h_T);
  hsplit_kernel<<<1, 256, 0, stream>>>(h_T, sT);
  h2bcast_kernel<<<S_N, 128, 0, stream>>>(sT, h2_a);

  for (int k = 0; k < PRED; k++) {
    const unsigned short* h_in = (k % 2 == 0) ? h2_a : h2_b;
    unsigned short* h_o = (k % 2 == 0) ? h2_b : h2_a;
    dec_gru_mfma<<<1024, 256, 0, stream>>>(
        h_in, Wr, giy + (size_t)k * 1536, b_hh, W_ih,
        (k == 0) ? x : tgt, (k == 0) ? 1 : 0, h_o);
    dec_head_kernel<<<1024, 64, 0, stream>>>(
        h_o, W_df, b_df, W_loc, b_loc, W_sc, b_sc, scale_p, tgt, out, k);
  }
}